// Round 13
// baseline (685.564 us; speedup 1.0000x reference)
//
#include <hip/hip_runtime.h>
#include <cstddef>

#define B 64
#define NC 10
#define L 900
#define SSTRIDE 36000  // stash stride: one f32 out_map image slice (bytes)

typedef float f32x4 __attribute__((ext_vector_type(4)));

// scratch tail offsets (floats, relative to scr = out_cw + 46,080,000)
#define SCR_COMB   0          // 3,686,400
#define SCR_S1     3686400    // 1,843,200
#define SCR_VE     5529600    // 640
#define SCR_S      5530240    // 400
#define SCR_WT2    5530640    // 18,432
#define SCR_WT1    5549072    // 18,432
#define SCR_BIAS1  5567504    // 32
#define SCR_GFP    5567536    // 61,440
#define SCR_CNT    5628976    // 640 ints  (end 5,629,616 < 5,760,000)

// ---- self-sufficient color_weights block (recomputes everything from inputs)
__device__ __forceinline__ void cw_block(int b, int rc,
                                         const float* __restrict__ g,
                                         const float* __restrict__ embed,
                                         const float* __restrict__ ipw,
                                         const float* __restrict__ ipb,
                                         float* __restrict__ out_cw,
                                         float* sm) {
  // sm layout (floats): qs 0..640, ks 640..1280, Sl 1280..1680, lut 1680..10680,
  // emb aliases 1680..2320 (dead before lut), cwb 10680, cf 10780, hist 10790,
  // cols (bytes) at 10800..11025
  float* qs = sm;
  float* ks = sm + 640;
  float* Sl = sm + 1280;
  float* lut = sm + 1680;
  float* emb = sm + 1680;
  float* cwb = sm + 10680;
  float* cf = sm + 10780;
  int* hist = (int*)(sm + 10790);
  unsigned char* cols = (unsigned char*)(sm + 10800);
  int t = threadIdx.x;
  for (int i = t; i < 640; i += 256) emb[i] = embed[i];
  if (t < 10) hist[t] = 0;
  __syncthreads();
  {  // q/k tables: row = t&127 (0..63 q, 64..127 k), 5 colors per half
    int row = t & 127, c0 = (t >> 7) * 5;
    const float* wrow = ipw + row * 64;
    float bias = ipb[row];
    for (int c = c0; c < c0 + 5; ++c) {
      float acc = bias;
      for (int j = 0; j < 64; ++j) acc += emb[c * 64 + j] * wrow[j];
      if (row < 64) qs[c * 64 + row] = acc;
      else ks[c * 64 + (row - 64)] = acc;
    }
  }
  const float* gb = g + (size_t)b * NC * L;
  for (int p = t; p < 900; p += 256) {
    float best = gb[p]; int bi = 0;
    for (int c = 1; c < NC; ++c) {
      float v = gb[c * L + p];
      if (v > best) { best = v; bi = c; }
    }
    cols[p] = (unsigned char)bi;
    atomicAdd(&hist[bi], 1);
  }
  __syncthreads();
  for (int i = t; i < 400; i += 256) {
    int h = i / 100, r = i % 100, cq = r / 10, ck = r % 10;
    float acc = 0.f;
    for (int e = 0; e < 16; ++e)
      acc += qs[cq * 64 + h * 16 + e] * ks[ck * 64 + h * 16 + e];
    Sl[i] = acc * 0.25f;
  }
  if (t < 10) cf[t] = (float)hist[t];
  __syncthreads();
  float* Al = qs;  // reuse (qs dead after Sl built)
  if (t < 40) {
    int h = t / 10, cq = t % 10;
    const float* Sr = Sl + h * 100 + cq * 10;
    float m = -1e30f;
    for (int c = 0; c < 10; ++c) if (cf[c] > 0.f) m = fmaxf(m, Sr[c]);
    float e[10]; float Z = 0.f;
    for (int c = 0; c < 10; ++c) { e[c] = expf(Sr[c] - m); Z += cf[c] * e[c]; }
    float inv = 1.f / Z;
    for (int c = 0; c < 10; ++c) Al[(h * 10 + cq) * 10 + c] = e[c] * inv;
  }
  __syncthreads();
  if (t < 100) {
    cwb[t] = 0.25f * (Al[t] + Al[100 + t] + Al[200 + t] + Al[300 + t]);
  }
  __syncthreads();
  for (int i = t; i < 9000; i += 256) {
    int cq = i / 900, p = i % 900;
    lut[cq * 900 + p] = cwb[cq * 10 + cols[p]];
  }
  __syncthreads();
  int base = rc * 15;
  for (int i = t; i < 15 * 225; i += 256) {
    int r = i / 225, ch = i % 225;
    int p = base + r;
    int cq = cols[p];
    f32x4 v = *(const f32x4*)&lut[cq * 900 + ch * 4];
    __builtin_nontemporal_store(v, (f32x4*)&out_cw[(size_t)b * 810000 + (size_t)p * 900 + ch * 4]);
  }
}

// ---- K front: tables | weights | idx/hist | conv1 -------------------------
__global__ __launch_bounds__(256) void k_front(
    const float* __restrict__ g, const float* __restrict__ embed,
    const float* __restrict__ ipw, const float* __restrict__ ipb,
    const float* __restrict__ cw1, const float* __restrict__ c1b,
    const float* __restrict__ cw2, const float* __restrict__ dw,
    const float* __restrict__ db, const float* __restrict__ bng,
    const float* __restrict__ bnb,
    float* __restrict__ scr, unsigned char* __restrict__ stash) {
  int bid = blockIdx.x, t = threadIdx.x;
  __shared__ float smem[4352];
  if (bid == 0) {
    float* emb = smem; float* q = smem + 640; float* k = smem + 1280;
    for (int i = t; i < 640; i += 256) emb[i] = embed[i];
    __syncthreads();
    for (int row = t; row < 192; row += 256) {
      int which = row >> 6, d = row & 63;
      for (int c = 0; c < 10; ++c) {
        float acc = ipb[row];
        for (int j = 0; j < 64; ++j) acc += emb[c * 64 + j] * ipw[row * 64 + j];
        if (which == 0) q[c * 64 + d] = acc;
        else if (which == 1) k[c * 64 + d] = acc;
        else scr[SCR_VE + c * 64 + d] = acc;
      }
    }
    __syncthreads();
    for (int i = t; i < 400; i += 256) {
      int h = i / 100, r = i % 100, cq = r / 10, ck = r % 10;
      float acc = 0.f;
      for (int e = 0; e < 16; ++e)
        acc += q[cq * 64 + h * 16 + e] * k[ck * 64 + h * 16 + e];
      scr[SCR_S + i] = acc * 0.25f;
    }
  } else if (bid <= 145) {
    int i = (bid - 1) * 256 + t;
    if (i < 18432) {
      int r = i / 64, oc = i % 64;
      scr[SCR_WT2 + r * 64 + oc] = cw2[oc * 288 + r];
    } else if (i < 36864) {
      int e = i - 18432, r = e / 32, oc = e % 32;
      int ic = r / 9, kk = r % 9, ky = kk / 3, kx = kk % 3;
      float s = bng[oc] / sqrtf(1.f + 1e-5f);
      scr[SCR_WT1 + r * 32 + oc] = dw[((ic * 32 + oc) * 3 + (2 - ky)) * 3 + (2 - kx)] * s;
    } else if (i < 36896) {
      int oc = i - 36864;
      float s = bng[oc] / sqrtf(1.f + 1e-5f);
      scr[SCR_BIAS1 + oc] = db[oc] * s + bnb[oc];
    }
  } else if (bid <= 209) {
    int b = bid - 146;
    int* hist = (int*)smem;
    int* cnt = (int*)(scr + SCR_CNT);
    if (t < 10) hist[t] = 0;
    __syncthreads();
    const float* gb = g + (size_t)b * NC * L;
    int* sidx = (int*)(stash + (size_t)b * SSTRIDE);
    for (int p = t; p < L; p += 256) {
      float best = gb[p]; int bi = 0;
      for (int c = 1; c < NC; ++c) {
        float v = gb[c * L + p];
        if (v > best) { best = v; bi = c; }
      }
      sidx[p] = bi;
      atomicAdd(&hist[bi], 1);
    }
    __syncthreads();
    if (t < 10) cnt[b * NC + t] = hist[t];
  } else {
    int blk = bid - 210, b = blk / 15, pr = blk % 15, oh0 = pr * 2;
    float* ins = smem;          // 1360
    float* ws = smem + 1360;    // 2880
    float* s1 = scr + SCR_S1;
    for (int i = t; i < 2880; i += 256) ws[i] = cw1[i];
    for (int e = t; e < 1360; e += 256) {
      int r = e / 340, rem = e % 340, ic = rem / 34, x = rem % 34;
      int y = oh0 + r - 1, gx = x - 1;
      float v = 0.f;
      if (y >= 0 && y < 30 && gx >= 0 && gx < 30)
        v = g[(size_t)(b * 10 + ic) * 900 + y * 30 + gx];
      ins[(r * 10 + ic) * 34 + x] = v;
    }
    __syncthreads();
    int lane = t & 63, ow = lane & 31, rr = lane >> 5;
    int oc0 = __builtin_amdgcn_readfirstlane((t >> 6) * 8);
    float acc[8];
    #pragma unroll
    for (int j = 0; j < 8; ++j) acc[j] = c1b[oc0 + j];
    for (int ic = 0; ic < 10; ++ic) {
      #pragma unroll
      for (int ky = 0; ky < 3; ++ky) {
        #pragma unroll
        for (int kx = 0; kx < 3; ++kx) {
          float iv = ins[((rr + ky) * 10 + ic) * 34 + ow + kx];
          #pragma unroll
          for (int j = 0; j < 8; ++j)
            acc[j] = fmaf(iv, ws[((oc0 + j) * 10 + ic) * 9 + ky * 3 + kx], acc[j]);
        }
      }
    }
    if (ow < 30) {
      #pragma unroll
      for (int j = 0; j < 8; ++j)
        s1[(size_t)(b * 32 + oc0 + j) * 900 + (oh0 + rr) * 30 + ow] = fmaxf(acc[j], 0.f);
    }
  }
}

// ---- K c2attn: local attn + conv2 + AT add + gf partials ------------------
__global__ __launch_bounds__(256) void k_c2attn(
    const float* __restrict__ scr_in, const float* __restrict__ cb,
    const float* __restrict__ opw, const float* __restrict__ opb,
    const unsigned char* __restrict__ stash,
    float* __restrict__ scr) {
  int blk = blockIdx.x, b = blk / 15, pr = blk % 15, oh0 = pr * 2;
  int t = threadIdx.x;
  const float* s1 = scr_in + SCR_S1;
  const float* S = scr_in + SCR_S;
  const float* ve = scr_in + SCR_VE;
  const int* cnt = (const int*)(scr_in + SCR_CNT);
  __shared__ float ins[4][32][34];
  __shared__ float A[4][10][10];
  __shared__ float cf[10];
  __shared__ float ctx[10][65];
  __shared__ float at[10][65];
  for (int e = t; e < 4352; e += 256) {
    int r = e / 1088, rem = e % 1088, ic = rem / 34, x = rem % 34;
    int y = oh0 + r - 1, gx = x - 1;
    float v = 0.f;
    if (y >= 0 && y < 30 && gx >= 0 && gx < 30)
      v = s1[(size_t)(b * 32 + ic) * 900 + y * 30 + gx];
    ins[r][ic][x] = v;
  }
  if (t < 10) cf[t] = (float)cnt[b * 10 + t];
  __syncthreads();
  if (t < 40) {
    int h = t / 10, cq = t % 10;
    const float* Sr = S + (h * 10 + cq) * 10;
    float m = -1e30f;
    for (int c = 0; c < 10; ++c) if (cf[c] > 0.f) m = fmaxf(m, Sr[c]);
    float e[10]; float Z = 0.f;
    for (int c = 0; c < 10; ++c) { e[c] = expf(Sr[c] - m); Z += cf[c] * e[c]; }
    float inv = 1.f / Z;
    for (int c = 0; c < 10; ++c) A[h][cq][c] = e[c] * inv;
  }
  __syncthreads();
  for (int i = t; i < 640; i += 256) {
    int cq = i >> 6, dd = i & 63, h = dd >> 4;
    float acc = 0.f;
    for (int ck = 0; ck < 10; ++ck) acc += A[h][cq][ck] * cf[ck] * ve[ck * 64 + dd];
    ctx[cq][dd] = acc;
  }
  __syncthreads();
  for (int i = t; i < 640; i += 256) {
    int cq = i >> 6, dd = i & 63;
    float acc = opb[dd];
    for (int e = 0; e < 64; ++e) acc += ctx[cq][e] * opw[dd * 64 + e];
    at[cq][dd] = acc;
  }
  __syncthreads();
  int lane = t & 63, ow = lane & 31, rr = lane >> 5;
  int oc0 = __builtin_amdgcn_readfirstlane((t >> 6) * 16);
  float acc[16];
  #pragma unroll
  for (int j = 0; j < 16; ++j) acc[j] = cb[oc0 + j];
  const float* wt2 = scr_in + SCR_WT2;
  for (int ic = 0; ic < 32; ++ic) {
    #pragma unroll
    for (int ky = 0; ky < 3; ++ky) {
      #pragma unroll
      for (int kx = 0; kx < 3; ++kx) {
        float iv = ins[rr + ky][ic][ow + kx];
        const float* wr = wt2 + (ic * 9 + ky * 3 + kx) * 64 + oc0;
        #pragma unroll
        for (int j = 0; j < 16; ++j) acc[j] = fmaf(iv, wr[j], acc[j]);
      }
    }
  }
  float outv[16];
  float* comb = scr + SCR_COMB;
  if (ow < 30) {
    const int* sidx = (const int*)(stash + (size_t)b * SSTRIDE);
    int c = sidx[(oh0 + rr) * 30 + ow];
    #pragma unroll
    for (int j = 0; j < 16; ++j) {
      outv[j] = fmaxf(acc[j], 0.f) + at[c][oc0 + j];
      comb[(size_t)(b * 64 + oc0 + j) * 900 + (oh0 + rr) * 30 + ow] = outv[j];
    }
  } else {
    #pragma unroll
    for (int j = 0; j < 16; ++j) outv[j] = 0.f;
  }
  #pragma unroll
  for (int j = 0; j < 16; ++j) {
    float v = outv[j];
    for (int o = 32; o; o >>= 1) v += __shfl_down(v, o, 64);
    if (lane == 0) scr[SCR_GFP + (b * 15 + pr) * 64 + oc0 + j] = v;
  }
}

// ---- K back: interleaved cw_head | d1+pred | mlp | map --------------------
// bid<3840: bid%4==3 -> d1 #(bid/4); else cw #((bid/4)*3 + bid%4)  [2880]
// bid 3840..4319: cw #(2880 + bid-3840)  [480 more -> 3360 total, images 0..55]
// bid 4320..4383: mlp | bid 4384..4447: map
__global__ __launch_bounds__(256) void k_back(
    const float* __restrict__ g, const float* __restrict__ embed,
    const float* __restrict__ ipw, const float* __restrict__ ipb,
    const float* __restrict__ scr,
    const float* __restrict__ l1w, const float* __restrict__ l1b,
    const float* __restrict__ l2w, const float* __restrict__ l2b,
    const float* __restrict__ w2, const float* __restrict__ b2,
    float* __restrict__ out_pred, float* __restrict__ out_cm,
    float* __restrict__ out_cw2, float* __restrict__ out_map,
    unsigned char* __restrict__ stash) {
  int bid = blockIdx.x, t = threadIdx.x;
  __shared__ float smem[11100];
  int cwid = -1, d1id = -1;
  if (bid < 3840) {
    if ((bid & 3) == 3) d1id = bid >> 2;
    else cwid = (bid >> 2) * 3 + (bid & 3);
  } else if (bid < 4320) {
    cwid = 2880 + (bid - 3840);
  }
  if (cwid >= 0) {
    cw_block(cwid / 60, cwid % 60, g, embed, ipw, ipb, out_cw2, smem);
  } else if (d1id >= 0) {
    int b = d1id / 15, pr = d1id % 15, oh0 = pr * 2;
    float* ins = smem;            // 8704
    float* d1s = smem + 8704;     // 2048
    const float* comb = scr + SCR_COMB;
    const float* wt1 = scr + SCR_WT1;
    const float* bias1 = scr + SCR_BIAS1;
    for (int e = t; e < 8704; e += 256) {
      int r = e / 2176, rem = e % 2176, ic = rem / 34, x = rem % 34;
      int y = oh0 + r - 1, gx = x - 1;
      float v = 0.f;
      if (y >= 0 && y < 30 && gx >= 0 && gx < 30)
        v = comb[(size_t)(b * 64 + ic) * 900 + y * 30 + gx];
      ins[(r * 64 + ic) * 34 + x] = v;
    }
    __syncthreads();
    int lane = t & 63, ow = lane & 31, rr = lane >> 5;
    int oc0 = __builtin_amdgcn_readfirstlane((t >> 6) * 8);
    float acc[8];
    #pragma unroll
    for (int j = 0; j < 8; ++j) acc[j] = bias1[oc0 + j];
    for (int ic = 0; ic < 64; ++ic) {
      #pragma unroll
      for (int ky = 0; ky < 3; ++ky) {
        #pragma unroll
        for (int kx = 0; kx < 3; ++kx) {
          float iv = ins[((rr + ky) * 64 + ic) * 34 + ow + kx];
          const float* wr = wt1 + (ic * 9 + ky * 3 + kx) * 32 + oc0;
          #pragma unroll
          for (int j = 0; j < 8; ++j) acc[j] = fmaf(iv, wr[j], acc[j]);
        }
      }
    }
    if (ow < 30) {
      #pragma unroll
      for (int j = 0; j < 8; ++j) d1s[(rr * 32 + oc0 + j) * 32 + ow] = fmaxf(acc[j], 0.f);
    }
    __syncthreads();
    for (int e = t; e < 600; e += 256) {
      int r = e / 300, rem = e % 300, o = rem / 30, ow2 = rem % 30;
      float a2 = b2[o];
      #pragma unroll
      for (int ic = 0; ic < 32; ++ic) a2 += d1s[(r * 32 + ic) * 32 + ow2] * w2[ic * 10 + o];
      out_pred[(size_t)(b * 10 + o) * 900 + (oh0 + r) * 30 + ow2] = a2;
    }
  } else if (bid < 4384) {
    int b = bid - 4320;
    float* gfl = smem; float* hmid = smem + 64; float* lg = smem + 192;
    const float* gfp = scr + SCR_GFP;
    if (t < 64) {
      float a = 0.f;
      for (int pr = 0; pr < 15; ++pr) a += gfp[(b * 15 + pr) * 64 + t];
      gfl[t] = a * (1.f / 900.f);
    }
    __syncthreads();
    if (t < 128) {
      float acc = l1b[t];
      for (int j = 0; j < 64; ++j) acc += gfl[j] * l1w[t * 64 + j];
      hmid[t] = fmaxf(acc, 0.f);
    }
    __syncthreads();
    if (t < 100) {
      float acc = l2b[t];
      for (int j = 0; j < 128; ++j) acc += hmid[j] * l2w[t * 128 + j];
      lg[t] = acc;
    }
    __syncthreads();
    if (t < 10) {
      float m = lg[t * 10];
      for (int j = 1; j < 10; ++j) m = fmaxf(m, lg[t * 10 + j]);
      float e[10]; float Z = 0.f;
      for (int j = 0; j < 10; ++j) { e[j] = expf(lg[t * 10 + j] - m); Z += e[j]; }
      float inv = 1.f / Z;
      for (int j = 0; j < 10; ++j) out_cm[(b * 10 + t) * 10 + j] = e[j] * inv;
    }
  } else {
    int b = bid - 4384;
    float* gfl = smem; float* hmid = smem + 64; float* lg = smem + 192;
    int* sn = (int*)(smem + 292);
    unsigned char* scol = (unsigned char*)(smem + 302);
    const float* gfp = scr + SCR_GFP;
    const int* sidx = (const int*)(stash + (size_t)b * SSTRIDE);
    for (int i = t; i < 900; i += 256) scol[i] = (unsigned char)sidx[i];
    if (t < 64) {
      float a = 0.f;
      for (int pr = 0; pr < 15; ++pr) a += gfp[(b * 15 + pr) * 64 + t];
      gfl[t] = a * (1.f / 900.f);
    }
    __syncthreads();
    if (t < 128) {
      float acc = l1b[t];
      for (int j = 0; j < 64; ++j) acc += gfl[j] * l1w[t * 64 + j];
      hmid[t] = fmaxf(acc, 0.f);
    }
    __syncthreads();
    if (t < 100) {
      float acc = l2b[t];
      for (int j = 0; j < 128; ++j) acc += hmid[j] * l2w[t * 128 + j];
      lg[t] = acc;
    }
    __syncthreads();
    if (t < 10) {
      float m = lg[t * 10]; int am = 0;
      for (int j = 1; j < 10; ++j) {
        float v = lg[t * 10 + j];
        if (v > m) { m = v; am = j; }
      }
      sn[t] = am;
    }
    __syncthreads();
    for (int i = t; i < 9000; i += 256) {
      int ch = i / 900, p = i % 900;
      out_map[(size_t)b * 9000 + i] = (sn[scol[p]] == ch) ? 1.0f : 0.0f;
    }
  }
}

// ---- K cwtail: self-sufficient cw for images 56..63 -----------------------
__global__ __launch_bounds__(256) void k_cwtail(
    const float* __restrict__ g, const float* __restrict__ embed,
    const float* __restrict__ ipw, const float* __restrict__ ipb,
    float* __restrict__ out_cw2) {
  __shared__ float smem[11100];
  int bid = blockIdx.x;
  cw_block(56 + bid / 60, bid % 60, g, embed, ipw, ipb, out_cw2, smem);
}

extern "C" void kernel_launch(void* const* d_in, const int* in_sizes, int n_in,
                              void* d_out, int out_size, void* d_ws, size_t ws_size,
                              hipStream_t stream) {
  const float* input_grid = (const float*)d_in[0];
  const float* embed      = (const float*)d_in[1];
  const float* in_proj_w  = (const float*)d_in[2];
  const float* in_proj_b  = (const float*)d_in[3];
  const float* out_proj_w = (const float*)d_in[4];
  const float* out_proj_b = (const float*)d_in[5];
  const float* conv1_w    = (const float*)d_in[6];
  const float* conv1_b    = (const float*)d_in[7];
  const float* conv2_w    = (const float*)d_in[8];
  const float* conv2_b    = (const float*)d_in[9];
  const float* lin1_w     = (const float*)d_in[10];
  const float* lin1_b     = (const float*)d_in[11];
  const float* lin2_w     = (const float*)d_in[12];
  const float* lin2_b     = (const float*)d_in[13];
  const float* dec1_w     = (const float*)d_in[14];
  const float* dec1_b     = (const float*)d_in[15];
  const float* bn_g       = (const float*)d_in[16];
  const float* bn_b       = (const float*)d_in[17];
  const float* dec2_w     = (const float*)d_in[18];
  const float* dec2_b     = (const float*)d_in[19];

  float* out      = (float*)d_out;
  float* out_pred = out;                  // 576,000
  float* out_cmap = out + 576000;         // 6,400
  float* out_cw   = out + 582400;         // 51,840,000
  float* out_map  = out + 52422400;       // 576,000

  // Scratch in the TAIL of out_cw (images >= 56.9): safe while k_back's
  // cw blocks write images 0..55; k_cwtail finishes 56..63 after scratch dies.
  float* scr = out_cw + 46080000;
  unsigned char* stash = (unsigned char*)out_map;  // idx only (3600 B/slice)

  k_front<<<1170, 256, 0, stream>>>(input_grid, embed, in_proj_w, in_proj_b,
                                    conv1_w, conv1_b, conv2_w, dec1_w, dec1_b,
                                    bn_g, bn_b, scr, stash);
  k_c2attn<<<960, 256, 0, stream>>>(scr, conv2_b, out_proj_w, out_proj_b,
                                    stash, scr);
  k_back<<<4448, 256, 0, stream>>>(input_grid, embed, in_proj_w, in_proj_b,
                                   scr, lin1_w, lin1_b, lin2_w, lin2_b,
                                   dec2_w, dec2_b, out_pred, out_cmap,
                                   out_cw, out_map, stash);
  k_cwtail<<<480, 256, 0, stream>>>(input_grid, embed, in_proj_w, in_proj_b,
                                    out_cw);
}

// Round 14
// 287.744 us; speedup vs baseline: 2.3825x; 2.3825x over previous
//
#include <hip/hip_runtime.h>
#include <cstddef>

#define B 64
#define NC 10
#define L 900
#define SSTRIDE 36000  // stash stride (bytes): one f32 out_map image slice
// stash slice layout: [0,900) cols bytes | [960,1360) scw 100 f32 | [1440,1480) ncol 10 int

typedef float f32x4 __attribute__((ext_vector_type(4)));

// scratch tail offsets (floats, relative to scr = out_cw + 46,080,000)
#define SCR_COMB   0          // 3,686,400
#define SCR_S1     3686400    // 1,843,200
#define SCR_VE     5529600    // 640
#define SCR_S      5530240    // 400
#define SCR_WT2    5530640    // 18,432
#define SCR_WT1    5549072    // 18,432
#define SCR_BIAS1  5567504    // 32
#define SCR_GFP    5567536    // 61,440
#define SCR_CNT    5628976    // 640 ints  (end 5,629,616 < 5,760,000)

// ---- stash-based color_weights block (verbatim R12 k_cw body) -------------
__device__ __forceinline__ void cw_store(int b, int rc,
                                         const unsigned char* __restrict__ stash,
                                         float* __restrict__ out_cw, float* sm) {
  // sm: lut[10*900] | cwb[100] at 9000 | cols bytes at 9104
  float* lut = sm;
  float* cwb = sm + 9000;
  unsigned char* cols = (unsigned char*)(sm + 9104);
  int t = threadIdx.x;
  const unsigned char* sl = stash + (size_t)b * SSTRIDE;
  const float* scw = (const float*)(sl + 960);
  for (int i = t; i < 900; i += 256) cols[i] = sl[i];
  for (int i = t; i < 100; i += 256) cwb[i] = scw[i];
  __syncthreads();
  for (int i = t; i < 9000; i += 256) {
    int cq = i / 900, p = i % 900;
    lut[cq * 900 + p] = cwb[cq * 10 + cols[p]];
  }
  __syncthreads();
  int base = rc * 15;
  for (int i = t; i < 15 * 225; i += 256) {
    int r = i / 225, ch = i % 225;
    int p = base + r;
    int cq = cols[p];
    f32x4 v = *(const f32x4*)&lut[cq * 900 + ch * 4];
    __builtin_nontemporal_store(v, (f32x4*)&out_cw[(size_t)b * 810000 + (size_t)p * 900 + ch * 4]);
  }
}

// ---- K front: tables | weights | argmax/hist | conv1 ----------------------
__global__ __launch_bounds__(256) void k_front(
    const float* __restrict__ g, const float* __restrict__ embed,
    const float* __restrict__ ipw, const float* __restrict__ ipb,
    const float* __restrict__ cw1, const float* __restrict__ c1b,
    const float* __restrict__ cw2, const float* __restrict__ dw,
    const float* __restrict__ db, const float* __restrict__ bng,
    const float* __restrict__ bnb,
    float* __restrict__ scr, unsigned char* __restrict__ stash) {
  int bid = blockIdx.x, t = threadIdx.x;
  __shared__ float smem[4352];
  if (bid == 0) {
    float* emb = smem; float* q = smem + 640; float* k = smem + 1280;
    for (int i = t; i < 640; i += 256) emb[i] = embed[i];
    __syncthreads();
    for (int row = t; row < 192; row += 256) {
      int which = row >> 6, d = row & 63;
      for (int c = 0; c < 10; ++c) {
        float acc = ipb[row];
        for (int j = 0; j < 64; ++j) acc += emb[c * 64 + j] * ipw[row * 64 + j];
        if (which == 0) q[c * 64 + d] = acc;
        else if (which == 1) k[c * 64 + d] = acc;
        else scr[SCR_VE + c * 64 + d] = acc;
      }
    }
    __syncthreads();
    for (int i = t; i < 400; i += 256) {
      int h = i / 100, r = i % 100, cq = r / 10, ck = r % 10;
      float acc = 0.f;
      for (int e = 0; e < 16; ++e)
        acc += q[cq * 64 + h * 16 + e] * k[ck * 64 + h * 16 + e];
      scr[SCR_S + i] = acc * 0.25f;
    }
  } else if (bid <= 145) {
    int i = (bid - 1) * 256 + t;
    if (i < 18432) {
      int r = i / 64, oc = i % 64;
      scr[SCR_WT2 + r * 64 + oc] = cw2[oc * 288 + r];
    } else if (i < 36864) {
      int e = i - 18432, r = e / 32, oc = e % 32;
      int ic = r / 9, kk = r % 9, ky = kk / 3, kx = kk % 3;
      float s = bng[oc] / sqrtf(1.f + 1e-5f);
      scr[SCR_WT1 + r * 32 + oc] = dw[((ic * 32 + oc) * 3 + (2 - ky)) * 3 + (2 - kx)] * s;
    } else if (i < 36896) {
      int oc = i - 36864;
      float s = bng[oc] / sqrtf(1.f + 1e-5f);
      scr[SCR_BIAS1 + oc] = db[oc] * s + bnb[oc];
    }
  } else if (bid <= 209) {
    int b = bid - 146;
    int* hist = (int*)smem;
    int* cnt = (int*)(scr + SCR_CNT);
    if (t < 10) hist[t] = 0;
    __syncthreads();
    const float* gb = g + (size_t)b * NC * L;
    unsigned char* cols = stash + (size_t)b * SSTRIDE;
    for (int p = t; p < L; p += 256) {
      float best = gb[p]; int bi = 0;
      for (int c = 1; c < NC; ++c) {
        float v = gb[c * L + p];
        if (v > best) { best = v; bi = c; }
      }
      cols[p] = (unsigned char)bi;
      atomicAdd(&hist[bi], 1);
    }
    __syncthreads();
    if (t < 10) cnt[b * NC + t] = hist[t];
  } else {
    int blk = bid - 210, b = blk / 15, pr = blk % 15, oh0 = pr * 2;
    float* ins = smem;          // 1360
    float* ws = smem + 1360;    // 2880
    float* s1 = scr + SCR_S1;
    for (int i = t; i < 2880; i += 256) ws[i] = cw1[i];
    for (int e = t; e < 1360; e += 256) {
      int r = e / 340, rem = e % 340, ic = rem / 34, x = rem % 34;
      int y = oh0 + r - 1, gx = x - 1;
      float v = 0.f;
      if (y >= 0 && y < 30 && gx >= 0 && gx < 30)
        v = g[(size_t)(b * 10 + ic) * 900 + y * 30 + gx];
      ins[(r * 10 + ic) * 34 + x] = v;
    }
    __syncthreads();
    int lane = t & 63, ow = lane & 31, rr = lane >> 5;
    int oc0 = __builtin_amdgcn_readfirstlane((t >> 6) * 8);
    float acc[8];
    #pragma unroll
    for (int j = 0; j < 8; ++j) acc[j] = c1b[oc0 + j];
    for (int ic = 0; ic < 10; ++ic) {
      #pragma unroll
      for (int ky = 0; ky < 3; ++ky) {
        #pragma unroll
        for (int kx = 0; kx < 3; ++kx) {
          float iv = ins[((rr + ky) * 10 + ic) * 34 + ow + kx];
          #pragma unroll
          for (int j = 0; j < 8; ++j)
            acc[j] = fmaf(iv, ws[((oc0 + j) * 10 + ic) * 9 + ky * 3 + kx], acc[j]);
        }
      }
    }
    if (ow < 30) {
      #pragma unroll
      for (int j = 0; j < 8; ++j)
        s1[(size_t)(b * 32 + oc0 + j) * 900 + (oh0 + rr) * 30 + ow] = fmaxf(acc[j], 0.f);
    }
  }
}

// ---- K c2attn: local attn + conv2 + AT add + gf partials + scw write ------
__global__ __launch_bounds__(256) void k_c2attn(
    const float* __restrict__ scr_in, const float* __restrict__ cb,
    const float* __restrict__ opw, const float* __restrict__ opb,
    unsigned char* __restrict__ stash, float* __restrict__ scr) {
  int blk = blockIdx.x, b = blk / 15, pr = blk % 15, oh0 = pr * 2;
  int t = threadIdx.x;
  const float* s1 = scr_in + SCR_S1;
  const float* S = scr_in + SCR_S;
  const float* ve = scr_in + SCR_VE;
  const int* cnt = (const int*)(scr_in + SCR_CNT);
  __shared__ float ins[4][32][34];
  __shared__ float A[4][10][10];
  __shared__ float cf[10];
  __shared__ float ctx[10][65];
  __shared__ float at[10][65];
  for (int e = t; e < 4352; e += 256) {
    int r = e / 1088, rem = e % 1088, ic = rem / 34, x = rem % 34;
    int y = oh0 + r - 1, gx = x - 1;
    float v = 0.f;
    if (y >= 0 && y < 30 && gx >= 0 && gx < 30)
      v = s1[(size_t)(b * 32 + ic) * 900 + y * 30 + gx];
    ins[r][ic][x] = v;
  }
  if (t < 10) cf[t] = (float)cnt[b * 10 + t];
  __syncthreads();
  if (t < 40) {
    int h = t / 10, cq = t % 10;
    const float* Sr = S + (h * 10 + cq) * 10;
    float m = -1e30f;
    for (int c = 0; c < 10; ++c) if (cf[c] > 0.f) m = fmaxf(m, Sr[c]);
    float e[10]; float Z = 0.f;
    for (int c = 0; c < 10; ++c) { e[c] = expf(Sr[c] - m); Z += cf[c] * e[c]; }
    float inv = 1.f / Z;
    for (int c = 0; c < 10; ++c) A[h][cq][c] = e[c] * inv;
  }
  __syncthreads();
  if (pr == 0 && t < 100) {
    int cq = t / 10, ck = t % 10;
    float* scw = (float*)(stash + (size_t)b * SSTRIDE + 960);
    scw[t] = 0.25f * (A[0][cq][ck] + A[1][cq][ck] + A[2][cq][ck] + A[3][cq][ck]);
  }
  for (int i = t; i < 640; i += 256) {
    int cq = i >> 6, dd = i & 63, h = dd >> 4;
    float acc = 0.f;
    for (int ck = 0; ck < 10; ++ck) acc += A[h][cq][ck] * cf[ck] * ve[ck * 64 + dd];
    ctx[cq][dd] = acc;
  }
  __syncthreads();
  for (int i = t; i < 640; i += 256) {
    int cq = i >> 6, dd = i & 63;
    float acc = opb[dd];
    for (int e = 0; e < 64; ++e) acc += ctx[cq][e] * opw[dd * 64 + e];
    at[cq][dd] = acc;
  }
  __syncthreads();
  int lane = t & 63, ow = lane & 31, rr = lane >> 5;
  int oc0 = __builtin_amdgcn_readfirstlane((t >> 6) * 16);
  float acc[16];
  #pragma unroll
  for (int j = 0; j < 16; ++j) acc[j] = cb[oc0 + j];
  const float* wt2 = scr_in + SCR_WT2;
  for (int ic = 0; ic < 32; ++ic) {
    #pragma unroll
    for (int ky = 0; ky < 3; ++ky) {
      #pragma unroll
      for (int kx = 0; kx < 3; ++kx) {
        float iv = ins[rr + ky][ic][ow + kx];
        const float* wr = wt2 + (ic * 9 + ky * 3 + kx) * 64 + oc0;
        #pragma unroll
        for (int j = 0; j < 16; ++j) acc[j] = fmaf(iv, wr[j], acc[j]);
      }
    }
  }
  float outv[16];
  float* comb = scr + SCR_COMB;
  if (ow < 30) {
    const unsigned char* cols = stash + (size_t)b * SSTRIDE;
    int c = cols[(oh0 + rr) * 30 + ow];
    #pragma unroll
    for (int j = 0; j < 16; ++j) {
      outv[j] = fmaxf(acc[j], 0.f) + at[c][oc0 + j];
      comb[(size_t)(b * 64 + oc0 + j) * 900 + (oh0 + rr) * 30 + ow] = outv[j];
    }
  } else {
    #pragma unroll
    for (int j = 0; j < 16; ++j) outv[j] = 0.f;
  }
  #pragma unroll
  for (int j = 0; j < 16; ++j) {
    float v = outv[j];
    for (int o = 32; o; o >>= 1) v += __shfl_down(v, o, 64);
    if (lane == 0) scr[SCR_GFP + (b * 15 + pr) * 64 + oc0 + j] = v;
  }
}

// ---- K back: interleaved cw(images 0..55) | d1+pred | mlp -----------------
// bid<3840: bid%4==3 -> d1 #(bid/4); else cw #((bid/4)*3 + bid%4)
// 3840..4319: cw #(2880+bid-3840) | 4320..4383: mlp
__global__ __launch_bounds__(256) void k_back(
    const float* __restrict__ scr,
    const float* __restrict__ l1w, const float* __restrict__ l1b,
    const float* __restrict__ l2w, const float* __restrict__ l2b,
    const float* __restrict__ w2, const float* __restrict__ b2,
    float* __restrict__ out_pred, float* __restrict__ out_cm,
    float* __restrict__ out_cw2, unsigned char* __restrict__ stash) {
  int bid = blockIdx.x, t = threadIdx.x;
  __shared__ float smem[10880];
  int cwid = -1, d1id = -1;
  if (bid < 3840) {
    if ((bid & 3) == 3) d1id = bid >> 2;
    else cwid = (bid >> 2) * 3 + (bid & 3);
  } else if (bid < 4320) {
    cwid = 2880 + (bid - 3840);
  }
  if (cwid >= 0) {
    cw_store(cwid / 60, cwid % 60, stash, out_cw2, smem);
  } else if (d1id >= 0) {
    int b = d1id / 15, pr = d1id % 15, oh0 = pr * 2;
    float* ins = smem;            // 8704
    float* d1s = smem + 8704;     // 2048
    const float* comb = scr + SCR_COMB;
    const float* wt1 = scr + SCR_WT1;
    const float* bias1 = scr + SCR_BIAS1;
    for (int e = t; e < 8704; e += 256) {
      int r = e / 2176, rem = e % 2176, ic = rem / 34, x = rem % 34;
      int y = oh0 + r - 1, gx = x - 1;
      float v = 0.f;
      if (y >= 0 && y < 30 && gx >= 0 && gx < 30)
        v = comb[(size_t)(b * 64 + ic) * 900 + y * 30 + gx];
      ins[(r * 64 + ic) * 34 + x] = v;
    }
    __syncthreads();
    int lane = t & 63, ow = lane & 31, rr = lane >> 5;
    int oc0 = __builtin_amdgcn_readfirstlane((t >> 6) * 8);
    float acc[8];
    #pragma unroll
    for (int j = 0; j < 8; ++j) acc[j] = bias1[oc0 + j];
    for (int ic = 0; ic < 64; ++ic) {
      #pragma unroll
      for (int ky = 0; ky < 3; ++ky) {
        #pragma unroll
        for (int kx = 0; kx < 3; ++kx) {
          float iv = ins[((rr + ky) * 64 + ic) * 34 + ow + kx];
          const float* wr = wt1 + (ic * 9 + ky * 3 + kx) * 32 + oc0;
          #pragma unroll
          for (int j = 0; j < 8; ++j) acc[j] = fmaf(iv, wr[j], acc[j]);
        }
      }
    }
    if (ow < 30) {
      #pragma unroll
      for (int j = 0; j < 8; ++j) d1s[(rr * 32 + oc0 + j) * 32 + ow] = fmaxf(acc[j], 0.f);
    }
    __syncthreads();
    for (int e = t; e < 600; e += 256) {
      int r = e / 300, rem = e % 300, o = rem / 30, ow2 = rem % 30;
      float a2 = b2[o];
      #pragma unroll
      for (int ic = 0; ic < 32; ++ic) a2 += d1s[(r * 32 + ic) * 32 + ow2] * w2[ic * 10 + o];
      out_pred[(size_t)(b * 10 + o) * 900 + (oh0 + r) * 30 + ow2] = a2;
    }
  } else {
    int b = bid - 4320;
    float* gfl = smem; float* hmid = smem + 64; float* lg = smem + 192;
    const float* gfp = scr + SCR_GFP;
    if (t < 64) {
      float a = 0.f;
      for (int pr = 0; pr < 15; ++pr) a += gfp[(b * 15 + pr) * 64 + t];
      gfl[t] = a * (1.f / 900.f);
    }
    __syncthreads();
    if (t < 128) {
      float acc = l1b[t];
      for (int j = 0; j < 64; ++j) acc += gfl[j] * l1w[t * 64 + j];
      hmid[t] = fmaxf(acc, 0.f);
    }
    __syncthreads();
    if (t < 100) {
      float acc = l2b[t];
      for (int j = 0; j < 128; ++j) acc += hmid[j] * l2w[t * 128 + j];
      lg[t] = acc;
    }
    __syncthreads();
    if (t < 10) {
      float m = lg[t * 10]; int am = 0;
      for (int j = 1; j < 10; ++j) {
        float v = lg[t * 10 + j];
        if (v > m) { m = v; am = j; }
      }
      float e[10]; float Z = 0.f;
      for (int j = 0; j < 10; ++j) { e[j] = expf(lg[t * 10 + j] - m); Z += e[j]; }
      float inv = 1.f / Z;
      for (int j = 0; j < 10; ++j) out_cm[(b * 10 + t) * 10 + j] = e[j] * inv;
      ((int*)(stash + (size_t)b * SSTRIDE + 1440))[t] = am;
    }
  }
}

// ---- K cwtail: cw for images 56..63 (after scratch dies) ------------------
__global__ __launch_bounds__(256) void k_cwtail(
    const unsigned char* __restrict__ stash, float* __restrict__ out_cw2) {
  __shared__ float smem[10880];
  int bid = blockIdx.x;
  cw_store(56 + bid / 60, bid % 60, stash, out_cw2, smem);
}

// ---- K map: one-hot mapped_output (reads own stash slice, overwrites it) --
__global__ void k_map(const unsigned char* __restrict__ stash,
                      float* __restrict__ out4) {
  int b = blockIdx.x, t = threadIdx.x;
  const unsigned char* sl = stash + (size_t)b * SSTRIDE;
  const int* sncol = (const int*)(sl + 1440);
  __shared__ unsigned char scol[900];
  __shared__ int sn[10];
  for (int i = t; i < 900; i += 256) scol[i] = sl[i];
  if (t < 10) sn[t] = sncol[t];
  __syncthreads();
  for (int i = t; i < 9000; i += 256) {
    int ch = i / 900, p = i % 900;
    out4[(size_t)b * 9000 + i] = (sn[scol[p]] == ch) ? 1.0f : 0.0f;
  }
}

extern "C" void kernel_launch(void* const* d_in, const int* in_sizes, int n_in,
                              void* d_out, int out_size, void* d_ws, size_t ws_size,
                              hipStream_t stream) {
  const float* input_grid = (const float*)d_in[0];
  const float* embed      = (const float*)d_in[1];
  const float* in_proj_w  = (const float*)d_in[2];
  const float* in_proj_b  = (const float*)d_in[3];
  const float* out_proj_w = (const float*)d_in[4];
  const float* out_proj_b = (const float*)d_in[5];
  const float* conv1_w    = (const float*)d_in[6];
  const float* conv1_b    = (const float*)d_in[7];
  const float* conv2_w    = (const float*)d_in[8];
  const float* conv2_b    = (const float*)d_in[9];
  const float* lin1_w     = (const float*)d_in[10];
  const float* lin1_b     = (const float*)d_in[11];
  const float* lin2_w     = (const float*)d_in[12];
  const float* lin2_b     = (const float*)d_in[13];
  const float* dec1_w     = (const float*)d_in[14];
  const float* dec1_b     = (const float*)d_in[15];
  const float* bn_g       = (const float*)d_in[16];
  const float* bn_b       = (const float*)d_in[17];
  const float* dec2_w     = (const float*)d_in[18];
  const float* dec2_b     = (const float*)d_in[19];

  float* out      = (float*)d_out;
  float* out_pred = out;                  // 576,000
  float* out_cmap = out + 576000;         // 6,400
  float* out_cw   = out + 582400;         // 51,840,000
  float* out_map  = out + 52422400;       // 576,000

  // Scratch in the TAIL of out_cw (images >= 56.9): k_back's cw blocks write
  // only images 0..55; k_cwtail (56..63) runs after scratch is dead.
  float* scr = out_cw + 46080000;
  unsigned char* stash = (unsigned char*)out_map;

  k_front<<<1170, 256, 0, stream>>>(input_grid, embed, in_proj_w, in_proj_b,
                                    conv1_w, conv1_b, conv2_w, dec1_w, dec1_b,
                                    bn_g, bn_b, scr, stash);
  k_c2attn<<<960, 256, 0, stream>>>(scr, conv2_b, out_proj_w, out_proj_b,
                                    stash, scr);
  k_back<<<4384, 256, 0, stream>>>(scr, lin1_w, lin1_b, lin2_w, lin2_b,
                                   dec2_w, dec2_b, out_pred, out_cmap,
                                   out_cw, stash);
  k_cwtail<<<480, 256, 0, stream>>>(stash, out_cw);
  k_map<<<B, 256, 0, stream>>>(stash, out_map);
}

// Round 15
// 213.760 us; speedup vs baseline: 3.2072x; 1.3461x over previous
//
#include <hip/hip_runtime.h>
#include <cstddef>

#define B 64
#define NC 10
#define L 900
#define SSTRIDE 36000  // stash stride (bytes): one f32 out_map image slice
// stash slice: [0,900) cols bytes | [960,1360) scw 100 f32 | [1440,1480) ncol 10 int

typedef float f32x4 __attribute__((ext_vector_type(4)));

// scratch tail offsets (floats, relative to scr = out_cw + 46,080,000)
#define SCR_COMB   0          // 3,686,400
#define SCR_S1     3686400    // 1,843,200
#define SCR_VE     5529600    // 640
#define SCR_S      5530240    // 400
#define SCR_WT2    5530640    // 18,432
#define SCR_WT1    5549072    // 18,432
#define SCR_BIAS1  5567504    // 32
#define SCR_GFP    5567536    // 61,440
#define SCR_CNT    5628976    // 640 ints  (end 5,629,616 < 5,760,000)

// ---- K front: tables | weights | argmax/hist | conv1 ----------------------
__global__ __launch_bounds__(256) void k_front(
    const float* __restrict__ g, const float* __restrict__ embed,
    const float* __restrict__ ipw, const float* __restrict__ ipb,
    const float* __restrict__ cw1, const float* __restrict__ c1b,
    const float* __restrict__ cw2, const float* __restrict__ dw,
    const float* __restrict__ db, const float* __restrict__ bng,
    const float* __restrict__ bnb,
    float* __restrict__ scr, unsigned char* __restrict__ stash) {
  int bid = blockIdx.x, t = threadIdx.x;
  __shared__ float smem[4352];
  if (bid == 0) {
    float* emb = smem; float* q = smem + 640; float* k = smem + 1280;
    for (int i = t; i < 640; i += 256) emb[i] = embed[i];
    __syncthreads();
    for (int row = t; row < 192; row += 256) {
      int which = row >> 6, d = row & 63;
      for (int c = 0; c < 10; ++c) {
        float acc = ipb[row];
        for (int j = 0; j < 64; ++j) acc += emb[c * 64 + j] * ipw[row * 64 + j];
        if (which == 0) q[c * 64 + d] = acc;
        else if (which == 1) k[c * 64 + d] = acc;
        else scr[SCR_VE + c * 64 + d] = acc;
      }
    }
    __syncthreads();
    for (int i = t; i < 400; i += 256) {
      int h = i / 100, r = i % 100, cq = r / 10, ck = r % 10;
      float acc = 0.f;
      for (int e = 0; e < 16; ++e)
        acc += q[cq * 64 + h * 16 + e] * k[ck * 64 + h * 16 + e];
      scr[SCR_S + i] = acc * 0.25f;
    }
  } else if (bid <= 145) {
    int i = (bid - 1) * 256 + t;
    if (i < 18432) {
      int r = i / 64, oc = i % 64;
      scr[SCR_WT2 + r * 64 + oc] = cw2[oc * 288 + r];
    } else if (i < 36864) {
      int e = i - 18432, r = e / 32, oc = e % 32;
      int ic = r / 9, kk = r % 9, ky = kk / 3, kx = kk % 3;
      float s = bng[oc] / sqrtf(1.f + 1e-5f);
      scr[SCR_WT1 + r * 32 + oc] = dw[((ic * 32 + oc) * 3 + (2 - ky)) * 3 + (2 - kx)] * s;
    } else if (i < 36896) {
      int oc = i - 36864;
      float s = bng[oc] / sqrtf(1.f + 1e-5f);
      scr[SCR_BIAS1 + oc] = db[oc] * s + bnb[oc];
    }
  } else if (bid <= 209) {
    int b = bid - 146;
    int* hist = (int*)smem;
    int* cnt = (int*)(scr + SCR_CNT);
    if (t < 10) hist[t] = 0;
    __syncthreads();
    const float* gb = g + (size_t)b * NC * L;
    unsigned char* cols = stash + (size_t)b * SSTRIDE;
    for (int p = t; p < L; p += 256) {
      float best = gb[p]; int bi = 0;
      for (int c = 1; c < NC; ++c) {
        float v = gb[c * L + p];
        if (v > best) { best = v; bi = c; }
      }
      cols[p] = (unsigned char)bi;
      atomicAdd(&hist[bi], 1);
    }
    __syncthreads();
    if (t < 10) cnt[b * NC + t] = hist[t];
  } else {
    int blk = bid - 210, b = blk / 15, pr = blk % 15, oh0 = pr * 2;
    float* ins = smem;          // 1360
    float* ws = smem + 1360;    // 2880
    float* s1 = scr + SCR_S1;
    for (int i = t; i < 2880; i += 256) ws[i] = cw1[i];
    for (int e = t; e < 1360; e += 256) {
      int r = e / 340, rem = e % 340, ic = rem / 34, x = rem % 34;
      int y = oh0 + r - 1, gx = x - 1;
      float v = 0.f;
      if (y >= 0 && y < 30 && gx >= 0 && gx < 30)
        v = g[(size_t)(b * 10 + ic) * 900 + y * 30 + gx];
      ins[(r * 10 + ic) * 34 + x] = v;
    }
    __syncthreads();
    int lane = t & 63, ow = lane & 31, rr = lane >> 5;
    int oc0 = __builtin_amdgcn_readfirstlane((t >> 6) * 8);
    float acc[8];
    #pragma unroll
    for (int j = 0; j < 8; ++j) acc[j] = c1b[oc0 + j];
    for (int ic = 0; ic < 10; ++ic) {
      #pragma unroll
      for (int ky = 0; ky < 3; ++ky) {
        #pragma unroll
        for (int kx = 0; kx < 3; ++kx) {
          float iv = ins[((rr + ky) * 10 + ic) * 34 + ow + kx];
          #pragma unroll
          for (int j = 0; j < 8; ++j)
            acc[j] = fmaf(iv, ws[((oc0 + j) * 10 + ic) * 9 + ky * 3 + kx], acc[j]);
        }
      }
    }
    if (ow < 30) {
      #pragma unroll
      for (int j = 0; j < 8; ++j)
        s1[(size_t)(b * 32 + oc0 + j) * 900 + (oh0 + rr) * 30 + ow] = fmaxf(acc[j], 0.f);
    }
  }
}

// ---- K c2attn: local attn + conv2 + AT add + gf partials + scw write ------
__global__ __launch_bounds__(256) void k_c2attn(
    const float* __restrict__ scr_in, const float* __restrict__ cb,
    const float* __restrict__ opw, const float* __restrict__ opb,
    unsigned char* __restrict__ stash, float* __restrict__ scr) {
  int blk = blockIdx.x, b = blk / 15, pr = blk % 15, oh0 = pr * 2;
  int t = threadIdx.x;
  const float* s1 = scr_in + SCR_S1;
  const float* S = scr_in + SCR_S;
  const float* ve = scr_in + SCR_VE;
  const int* cnt = (const int*)(scr_in + SCR_CNT);
  __shared__ float ins[4][32][34];
  __shared__ float A[4][10][10];
  __shared__ float cf[10];
  __shared__ float ctx[10][65];
  __shared__ float at[10][65];
  for (int e = t; e < 4352; e += 256) {
    int r = e / 1088, rem = e % 1088, ic = rem / 34, x = rem % 34;
    int y = oh0 + r - 1, gx = x - 1;
    float v = 0.f;
    if (y >= 0 && y < 30 && gx >= 0 && gx < 30)
      v = s1[(size_t)(b * 32 + ic) * 900 + y * 30 + gx];
    ins[r][ic][x] = v;
  }
  if (t < 10) cf[t] = (float)cnt[b * 10 + t];
  __syncthreads();
  if (t < 40) {
    int h = t / 10, cq = t % 10;
    const float* Sr = S + (h * 10 + cq) * 10;
    float m = -1e30f;
    for (int c = 0; c < 10; ++c) if (cf[c] > 0.f) m = fmaxf(m, Sr[c]);
    float e[10]; float Z = 0.f;
    for (int c = 0; c < 10; ++c) { e[c] = expf(Sr[c] - m); Z += cf[c] * e[c]; }
    float inv = 1.f / Z;
    for (int c = 0; c < 10; ++c) A[h][cq][c] = e[c] * inv;
  }
  __syncthreads();
  if (pr == 0 && t < 100) {
    int cq = t / 10, ck = t % 10;
    float* scw = (float*)(stash + (size_t)b * SSTRIDE + 960);
    scw[t] = 0.25f * (A[0][cq][ck] + A[1][cq][ck] + A[2][cq][ck] + A[3][cq][ck]);
  }
  for (int i = t; i < 640; i += 256) {
    int cq = i >> 6, dd = i & 63, h = dd >> 4;
    float acc = 0.f;
    for (int ck = 0; ck < 10; ++ck) acc += A[h][cq][ck] * cf[ck] * ve[ck * 64 + dd];
    ctx[cq][dd] = acc;
  }
  __syncthreads();
  for (int i = t; i < 640; i += 256) {
    int cq = i >> 6, dd = i & 63;
    float acc = opb[dd];
    for (int e = 0; e < 64; ++e) acc += ctx[cq][e] * opw[dd * 64 + e];
    at[cq][dd] = acc;
  }
  __syncthreads();
  int lane = t & 63, ow = lane & 31, rr = lane >> 5;
  int oc0 = __builtin_amdgcn_readfirstlane((t >> 6) * 16);
  float acc[16];
  #pragma unroll
  for (int j = 0; j < 16; ++j) acc[j] = cb[oc0 + j];
  const float* wt2 = scr_in + SCR_WT2;
  for (int ic = 0; ic < 32; ++ic) {
    #pragma unroll
    for (int ky = 0; ky < 3; ++ky) {
      #pragma unroll
      for (int kx = 0; kx < 3; ++kx) {
        float iv = ins[rr + ky][ic][ow + kx];
        const float* wr = wt2 + (ic * 9 + ky * 3 + kx) * 64 + oc0;
        #pragma unroll
        for (int j = 0; j < 16; ++j) acc[j] = fmaf(iv, wr[j], acc[j]);
      }
    }
  }
  float outv[16];
  float* comb = scr + SCR_COMB;
  if (ow < 30) {
    const unsigned char* cols = stash + (size_t)b * SSTRIDE;
    int c = cols[(oh0 + rr) * 30 + ow];
    #pragma unroll
    for (int j = 0; j < 16; ++j) {
      outv[j] = fmaxf(acc[j], 0.f) + at[c][oc0 + j];
      comb[(size_t)(b * 64 + oc0 + j) * 900 + (oh0 + rr) * 30 + ow] = outv[j];
    }
  } else {
    #pragma unroll
    for (int j = 0; j < 16; ++j) outv[j] = 0.f;
  }
  #pragma unroll
  for (int j = 0; j < 16; ++j) {
    float v = outv[j];
    for (int o = 32; o; o >>= 1) v += __shfl_down(v, o, 64);
    if (lane == 0) scr[SCR_GFP + (b * 15 + pr) * 64 + oc0 + j] = v;
  }
}

// ---- K back: mlp (blocks 0..63) | d1+pred (blocks 64..1023) ---------------
__global__ __launch_bounds__(256) void k_back(
    const float* __restrict__ scr,
    const float* __restrict__ l1w, const float* __restrict__ l1b,
    const float* __restrict__ l2w, const float* __restrict__ l2b,
    const float* __restrict__ w2, const float* __restrict__ b2,
    float* __restrict__ out_pred, float* __restrict__ out_cm,
    unsigned char* __restrict__ stash) {
  int bid = blockIdx.x, t = threadIdx.x;
  __shared__ float smem[10880];
  if (bid < 64) {
    int b = bid;
    float* gfl = smem; float* hmid = smem + 64; float* lg = smem + 192;
    const float* gfp = scr + SCR_GFP;
    if (t < 64) {
      float a = 0.f;
      for (int pr = 0; pr < 15; ++pr) a += gfp[(b * 15 + pr) * 64 + t];
      gfl[t] = a * (1.f / 900.f);
    }
    __syncthreads();
    if (t < 128) {
      float acc = l1b[t];
      for (int j = 0; j < 64; ++j) acc += gfl[j] * l1w[t * 64 + j];
      hmid[t] = fmaxf(acc, 0.f);
    }
    __syncthreads();
    if (t < 100) {
      float acc = l2b[t];
      for (int j = 0; j < 128; ++j) acc += hmid[j] * l2w[t * 128 + j];
      lg[t] = acc;
    }
    __syncthreads();
    if (t < 10) {
      float m = lg[t * 10]; int am = 0;
      for (int j = 1; j < 10; ++j) {
        float v = lg[t * 10 + j];
        if (v > m) { m = v; am = j; }
      }
      float e[10]; float Z = 0.f;
      for (int j = 0; j < 10; ++j) { e[j] = expf(lg[t * 10 + j] - m); Z += e[j]; }
      float inv = 1.f / Z;
      for (int j = 0; j < 10; ++j) out_cm[(b * 10 + t) * 10 + j] = e[j] * inv;
      ((int*)(stash + (size_t)b * SSTRIDE + 1440))[t] = am;
    }
  } else {
    int blk = bid - 64, b = blk / 15, pr = blk % 15, oh0 = pr * 2;
    float* ins = smem;            // 8704
    float* d1s = smem + 8704;     // 2048
    const float* comb = scr + SCR_COMB;
    const float* wt1 = scr + SCR_WT1;
    const float* bias1 = scr + SCR_BIAS1;
    for (int e = t; e < 8704; e += 256) {
      int r = e / 2176, rem = e % 2176, ic = rem / 34, x = rem % 34;
      int y = oh0 + r - 1, gx = x - 1;
      float v = 0.f;
      if (y >= 0 && y < 30 && gx >= 0 && gx < 30)
        v = comb[(size_t)(b * 64 + ic) * 900 + y * 30 + gx];
      ins[(r * 64 + ic) * 34 + x] = v;
    }
    __syncthreads();
    int lane = t & 63, ow = lane & 31, rr = lane >> 5;
    int oc0 = __builtin_amdgcn_readfirstlane((t >> 6) * 8);
    float acc[8];
    #pragma unroll
    for (int j = 0; j < 8; ++j) acc[j] = bias1[oc0 + j];
    for (int ic = 0; ic < 64; ++ic) {
      #pragma unroll
      for (int ky = 0; ky < 3; ++ky) {
        #pragma unroll
        for (int kx = 0; kx < 3; ++kx) {
          float iv = ins[((rr + ky) * 64 + ic) * 34 + ow + kx];
          const float* wr = wt1 + (ic * 9 + ky * 3 + kx) * 32 + oc0;
          #pragma unroll
          for (int j = 0; j < 8; ++j) acc[j] = fmaf(iv, wr[j], acc[j]);
        }
      }
    }
    if (ow < 30) {
      #pragma unroll
      for (int j = 0; j < 8; ++j) d1s[(rr * 32 + oc0 + j) * 32 + ow] = fmaxf(acc[j], 0.f);
    }
    __syncthreads();
    for (int e = t; e < 600; e += 256) {
      int r = e / 300, rem = e % 300, o = rem / 30, ow2 = rem % 30;
      float a2 = b2[o];
      #pragma unroll
      for (int ic = 0; ic < 32; ++ic) a2 += d1s[(r * 32 + ic) * 32 + ow2] * w2[ic * 10 + o];
      out_pred[(size_t)(b * 10 + o) * 900 + (oh0 + r) * 30 + ow2] = a2;
    }
  }
}

// ---- K cw: broadcast color_weights (3840 standalone blocks) ---------------
__global__ __launch_bounds__(256) void k_cw(
    const unsigned char* __restrict__ stash, float* __restrict__ out2) {
  int blk = blockIdx.x;
  int b = blk / 60, rc = blk % 60;
  int t = threadIdx.x;
  const unsigned char* sl = stash + (size_t)b * SSTRIDE;
  const float* scw = (const float*)(sl + 960);
  __shared__ float lut[10][900];
  __shared__ unsigned char cols[900];
  __shared__ float cwb[100];
  for (int i = t; i < 900; i += 256) cols[i] = sl[i];
  for (int i = t; i < 100; i += 256) cwb[i] = scw[i];
  __syncthreads();
  for (int i = t; i < 9000; i += 256) {
    int cq = i / 900, p = i % 900;
    lut[cq][p] = cwb[cq * 10 + cols[p]];
  }
  __syncthreads();
  int base = rc * 15;
  for (int i = t; i < 15 * 225; i += 256) {
    int r = i / 225, ch = i % 225;
    int p = base + r;
    int cq = cols[p];
    f32x4 v = *(const f32x4*)&lut[cq][ch * 4];
    __builtin_nontemporal_store(v, (f32x4*)&out2[(size_t)b * 810000 + (size_t)p * 900 + ch * 4]);
  }
}

// ---- K map: one-hot mapped_output (reads own stash slice, overwrites it) --
__global__ void k_map(const unsigned char* __restrict__ stash,
                      float* __restrict__ out4) {
  int b = blockIdx.x, t = threadIdx.x;
  const unsigned char* sl = stash + (size_t)b * SSTRIDE;
  const int* sncol = (const int*)(sl + 1440);
  __shared__ unsigned char scol[900];
  __shared__ int sn[10];
  for (int i = t; i < 900; i += 256) scol[i] = sl[i];
  if (t < 10) sn[t] = sncol[t];
  __syncthreads();
  for (int i = t; i < 9000; i += 256) {
    int ch = i / 900, p = i % 900;
    out4[(size_t)b * 9000 + i] = (sn[scol[p]] == ch) ? 1.0f : 0.0f;
  }
}

extern "C" void kernel_launch(void* const* d_in, const int* in_sizes, int n_in,
                              void* d_out, int out_size, void* d_ws, size_t ws_size,
                              hipStream_t stream) {
  const float* input_grid = (const float*)d_in[0];
  const float* embed      = (const float*)d_in[1];
  const float* in_proj_w  = (const float*)d_in[2];
  const float* in_proj_b  = (const float*)d_in[3];
  const float* out_proj_w = (const float*)d_in[4];
  const float* out_proj_b = (const float*)d_in[5];
  const float* conv1_w    = (const float*)d_in[6];
  const float* conv1_b    = (const float*)d_in[7];
  const float* conv2_w    = (const float*)d_in[8];
  const float* conv2_b    = (const float*)d_in[9];
  const float* lin1_w     = (const float*)d_in[10];
  const float* lin1_b     = (const float*)d_in[11];
  const float* lin2_w     = (const float*)d_in[12];
  const float* lin2_b     = (const float*)d_in[13];
  const float* dec1_w     = (const float*)d_in[14];
  const float* dec1_b     = (const float*)d_in[15];
  const float* bn_g       = (const float*)d_in[16];
  const float* bn_b       = (const float*)d_in[17];
  const float* dec2_w     = (const float*)d_in[18];
  const float* dec2_b     = (const float*)d_in[19];

  float* out      = (float*)d_out;
  float* out_pred = out;                  // 576,000
  float* out_cmap = out + 576000;         // 6,400
  float* out_cw   = out + 582400;         // 51,840,000
  float* out_map  = out + 52422400;       // 576,000

  // Scratch in the TAIL of out_cw; fully dead before k_cw runs (k_cw is
  // after k_back, the last scratch reader).
  float* scr = out_cw + 46080000;
  unsigned char* stash = (unsigned char*)out_map;

  k_front<<<1170, 256, 0, stream>>>(input_grid, embed, in_proj_w, in_proj_b,
                                    conv1_w, conv1_b, conv2_w, dec1_w, dec1_b,
                                    bn_g, bn_b, scr, stash);
  k_c2attn<<<960, 256, 0, stream>>>(scr, conv2_b, out_proj_w, out_proj_b,
                                    stash, scr);
  k_back<<<1024, 256, 0, stream>>>(scr, lin1_w, lin1_b, lin2_w, lin2_b,
                                   dec2_w, dec2_b, out_pred, out_cmap, stash);
  k_cw<<<B * 60, 256, 0, stream>>>(stash, out_cw);
  k_map<<<B, 256, 0, stream>>>(stash, out_map);
}

// Round 16
// 211.682 us; speedup vs baseline: 3.2386x; 1.0098x over previous
//
#include <hip/hip_runtime.h>
#include <cstddef>

#define B 64
#define NC 10
#define L 900

typedef float f32x4 __attribute__((ext_vector_type(4)));

// ---- K front: block-specialized independent setup work --------------------
// blocks 0: qkv/score tables | 1..145: wt2/wt1/bias1 | 146..209: per-image
// argmax+hist | 210..1169: conv1
__global__ __launch_bounds__(256) void k_front(
    const float* __restrict__ g, const float* __restrict__ embed,
    const float* __restrict__ ipw, const float* __restrict__ ipb,
    const float* __restrict__ cw1, const float* __restrict__ c1b,
    const float* __restrict__ cw2, const float* __restrict__ dw,
    const float* __restrict__ db, const float* __restrict__ bng,
    const float* __restrict__ bnb,
    float* __restrict__ ve_g, float* __restrict__ S_g,
    float* __restrict__ wt2, float* __restrict__ wt1,
    float* __restrict__ bias1, int* __restrict__ cnt,
    float* __restrict__ s1, unsigned char* __restrict__ stash,
    int sstride) {
  int bid = blockIdx.x, t = threadIdx.x;
  __shared__ float smem[4352];
  if (bid == 0) {
    float* emb = smem; float* q = smem + 640; float* k = smem + 1280;
    for (int i = t; i < 640; i += 256) emb[i] = embed[i];
    __syncthreads();
    for (int row = t; row < 192; row += 256) {
      int which = row >> 6, d = row & 63;
      for (int c = 0; c < 10; ++c) {
        float acc = ipb[row];
        for (int j = 0; j < 64; ++j) acc += emb[c * 64 + j] * ipw[row * 64 + j];
        if (which == 0) q[c * 64 + d] = acc;
        else if (which == 1) k[c * 64 + d] = acc;
        else ve_g[c * 64 + d] = acc;
      }
    }
    __syncthreads();
    for (int i = t; i < 400; i += 256) {
      int h = i / 100, r = i % 100, cq = r / 10, ck = r % 10;
      float acc = 0.f;
      for (int e = 0; e < 16; ++e)
        acc += q[cq * 64 + h * 16 + e] * k[ck * 64 + h * 16 + e];
      S_g[i] = acc * 0.25f;
    }
  } else if (bid <= 145) {
    int i = (bid - 1) * 256 + t;
    if (i < 18432) {
      int r = i / 64, oc = i % 64;
      wt2[r * 64 + oc] = cw2[oc * 288 + r];
    } else if (i < 36864) {
      int e = i - 18432, r = e / 32, oc = e % 32;
      int ic = r / 9, kk = r % 9, ky = kk / 3, kx = kk % 3;
      float s = bng[oc] / sqrtf(1.f + 1e-5f);
      wt1[r * 32 + oc] = dw[((ic * 32 + oc) * 3 + (2 - ky)) * 3 + (2 - kx)] * s;
    } else if (i < 36896) {
      int oc = i - 36864;
      float s = bng[oc] / sqrtf(1.f + 1e-5f);
      bias1[oc] = db[oc] * s + bnb[oc];
    }
  } else if (bid <= 209) {
    int b = bid - 146;
    int* hist = (int*)smem;
    if (t < 10) hist[t] = 0;
    __syncthreads();
    const float* gb = g + (size_t)b * NC * L;
    int* sidx = (int*)(stash + (size_t)b * sstride);
    for (int p = t; p < L; p += 256) {
      float best = gb[p]; int bi = 0;
      for (int c = 1; c < NC; ++c) {
        float v = gb[c * L + p];
        if (v > best) { best = v; bi = c; }
      }
      sidx[p] = bi;
      atomicAdd(&hist[bi], 1);
    }
    __syncthreads();
    if (t < 10) cnt[b * NC + t] = hist[t];
  } else {
    int blk = bid - 210, b = blk / 15, pr = blk % 15, oh0 = pr * 2;
    float* ins = smem;          // [4][10][34] = 1360
    float* ws = smem + 1360;    // 2880 raw conv1_w
    for (int i = t; i < 2880; i += 256) ws[i] = cw1[i];
    for (int e = t; e < 1360; e += 256) {
      int r = e / 340, rem = e % 340, ic = rem / 34, x = rem % 34;
      int y = oh0 + r - 1, gx = x - 1;
      float v = 0.f;
      if (y >= 0 && y < 30 && gx >= 0 && gx < 30)
        v = g[(size_t)(b * 10 + ic) * 900 + y * 30 + gx];
      ins[(r * 10 + ic) * 34 + x] = v;
    }
    __syncthreads();
    int lane = t & 63, ow = lane & 31, rr = lane >> 5;
    int oc0 = __builtin_amdgcn_readfirstlane((t >> 6) * 8);
    float acc[8];
    #pragma unroll
    for (int j = 0; j < 8; ++j) acc[j] = c1b[oc0 + j];
    for (int ic = 0; ic < 10; ++ic) {
      #pragma unroll
      for (int ky = 0; ky < 3; ++ky) {
        #pragma unroll
        for (int kx = 0; kx < 3; ++kx) {
          float iv = ins[((rr + ky) * 10 + ic) * 34 + ow + kx];
          #pragma unroll
          for (int j = 0; j < 8; ++j)
            acc[j] = fmaf(iv, ws[((oc0 + j) * 10 + ic) * 9 + ky * 3 + kx], acc[j]);
        }
      }
    }
    if (ow < 30) {
      #pragma unroll
      for (int j = 0; j < 8; ++j)
        s1[(size_t)(b * 32 + oc0 + j) * 900 + (oh0 + rr) * 30 + ow] = fmaxf(acc[j], 0.f);
    }
  }
}

// ---- K attn: per-image A, CW->stash, ctx, AT ------------------------------
__global__ void k_attn(const float* __restrict__ S, const float* __restrict__ ve,
                       const int* __restrict__ cnt,
                       const float* __restrict__ opw, const float* __restrict__ opb,
                       float* __restrict__ AT, unsigned char* __restrict__ stash,
                       int sstride) {
  int b = blockIdx.x, t = threadIdx.x;  // 128 threads
  float* scw = (float*)(stash + (size_t)b * sstride + 3640);
  __shared__ float A[4][10][10];
  __shared__ float cf[10];
  __shared__ float ctx[10][64];
  if (t < 10) cf[t] = (float)cnt[b * 10 + t];
  __syncthreads();
  if (t < 40) {
    int h = t / 10, cq = t % 10;
    const float* Sr = S + (h * 10 + cq) * 10;
    float m = -1e30f;
    for (int c = 0; c < 10; ++c) if (cf[c] > 0.f) m = fmaxf(m, Sr[c]);
    float e[10]; float Z = 0.f;
    for (int c = 0; c < 10; ++c) { e[c] = expf(Sr[c] - m); Z += cf[c] * e[c]; }
    float inv = 1.f / Z;
    for (int c = 0; c < 10; ++c) A[h][cq][c] = e[c] * inv;
  }
  __syncthreads();
  if (t < 100) {
    int cq = t / 10, ck = t % 10;
    scw[t] = 0.25f * (A[0][cq][ck] + A[1][cq][ck] + A[2][cq][ck] + A[3][cq][ck]);
  }
  for (int i = t; i < 640; i += 128) {
    int cq = i >> 6, dd = i & 63, h = dd >> 4;
    float acc = 0.f;
    for (int ck = 0; ck < 10; ++ck) acc += A[h][cq][ck] * cf[ck] * ve[ck * 64 + dd];
    ctx[cq][dd] = acc;
  }
  __syncthreads();
  for (int i = t; i < 640; i += 128) {
    int cq = i >> 6, dd = i & 63;
    float acc = opb[dd];
    for (int e = 0; e < 64; ++e) acc += ctx[cq][e] * opw[dd * 64 + e];
    AT[(b * 10 + cq) * 64 + dd] = acc;
  }
}

// ---- K c2: conv2 32->64 + relu + AT add + gf partial reduce ---------------
__global__ __launch_bounds__(256) void k_c2(const float* __restrict__ s1,
                                            const float* __restrict__ wt2,
                                            const float* __restrict__ cb,
                                            const float* __restrict__ AT,
                                            const unsigned char* __restrict__ stash,
                                            int sstride,
                                            float* __restrict__ comb,
                                            float* __restrict__ gfp) {
  int blk = blockIdx.x, b = blk / 15, pr = blk % 15, oh0 = pr * 2;
  int t = threadIdx.x;
  __shared__ float ins[4][32][34];
  for (int e = t; e < 4352; e += 256) {
    int r = e / 1088, rem = e % 1088, ic = rem / 34, x = rem % 34;
    int y = oh0 + r - 1, gx = x - 1;
    float v = 0.f;
    if (y >= 0 && y < 30 && gx >= 0 && gx < 30)
      v = s1[(size_t)(b * 32 + ic) * 900 + y * 30 + gx];
    ins[r][ic][x] = v;
  }
  __syncthreads();
  int lane = t & 63, ow = lane & 31, rr = lane >> 5;
  int oc0 = __builtin_amdgcn_readfirstlane((t >> 6) * 16);
  float acc[16];
  #pragma unroll
  for (int j = 0; j < 16; ++j) acc[j] = cb[oc0 + j];
  for (int ic = 0; ic < 32; ++ic) {
    #pragma unroll
    for (int ky = 0; ky < 3; ++ky) {
      #pragma unroll
      for (int kx = 0; kx < 3; ++kx) {
        float iv = ins[rr + ky][ic][ow + kx];
        const float* wr = wt2 + (ic * 9 + ky * 3 + kx) * 64 + oc0;
        #pragma unroll
        for (int j = 0; j < 16; ++j) acc[j] = fmaf(iv, wr[j], acc[j]);
      }
    }
  }
  float outv[16];
  if (ow < 30) {
    const int* sidx = (const int*)(stash + (size_t)b * sstride);
    int c = sidx[(oh0 + rr) * 30 + ow];
    const float* atp = AT + ((size_t)b * 10 + c) * 64 + oc0;
    #pragma unroll
    for (int j = 0; j < 16; ++j) {
      outv[j] = fmaxf(acc[j], 0.f) + atp[j];
      comb[(size_t)(b * 64 + oc0 + j) * 900 + (oh0 + rr) * 30 + ow] = outv[j];
    }
  } else {
    #pragma unroll
    for (int j = 0; j < 16; ++j) outv[j] = 0.f;
  }
  #pragma unroll
  for (int j = 0; j < 16; ++j) {
    float v = outv[j];
    for (int o = 32; o; o >>= 1) v += __shfl_down(v, o, 64);
    if (lane == 0) gfp[(b * 15 + pr) * 64 + oc0 + j] = v;
  }
}

// ---- K back: blocks 0..63 mlp | 64..1023 d1+pred --------------------------
__global__ __launch_bounds__(256) void k_back(
    const float* __restrict__ comb, const float* __restrict__ wt1,
    const float* __restrict__ bias1, const float* __restrict__ gfp,
    const float* __restrict__ l1w, const float* __restrict__ l1b,
    const float* __restrict__ l2w, const float* __restrict__ l2b,
    const float* __restrict__ w2, const float* __restrict__ b2,
    float* __restrict__ out_pred, float* __restrict__ out_cm,
    unsigned char* __restrict__ stash, int sstride) {
  int bid = blockIdx.x, t = threadIdx.x;
  __shared__ float smem[10880];
  if (bid < 64) {
    int b = bid;
    float* gfl = smem; float* hmid = smem + 64; float* lg = smem + 192;
    if (t < 64) {
      float a = 0.f;
      for (int pr = 0; pr < 15; ++pr) a += gfp[(b * 15 + pr) * 64 + t];
      gfl[t] = a * (1.f / 900.f);
    }
    __syncthreads();
    if (t < 128) {
      float acc = l1b[t];
      for (int j = 0; j < 64; ++j) acc += gfl[j] * l1w[t * 64 + j];
      hmid[t] = fmaxf(acc, 0.f);
    }
    __syncthreads();
    if (t < 100) {
      float acc = l2b[t];
      for (int j = 0; j < 128; ++j) acc += hmid[j] * l2w[t * 128 + j];
      lg[t] = acc;
    }
    __syncthreads();
    if (t < 10) {
      float m = lg[t * 10]; int am = 0;
      for (int j = 1; j < 10; ++j) {
        float v = lg[t * 10 + j];
        if (v > m) { m = v; am = j; }
      }
      float e[10]; float Z = 0.f;
      for (int j = 0; j < 10; ++j) { e[j] = expf(lg[t * 10 + j] - m); Z += e[j]; }
      float inv = 1.f / Z;
      for (int j = 0; j < 10; ++j) out_cm[(b * 10 + t) * 10 + j] = e[j] * inv;
      ((int*)(stash + (size_t)b * sstride + 3600))[t] = am;
    }
  } else {
    int blk = bid - 64, b = blk / 15, pr = blk % 15, oh0 = pr * 2;
    float* ins = smem;            // 8704
    float* d1s = smem + 8704;     // 2048
    for (int e = t; e < 8704; e += 256) {
      int r = e / 2176, rem = e % 2176, ic = rem / 34, x = rem % 34;
      int y = oh0 + r - 1, gx = x - 1;
      float v = 0.f;
      if (y >= 0 && y < 30 && gx >= 0 && gx < 30)
        v = comb[(size_t)(b * 64 + ic) * 900 + y * 30 + gx];
      ins[(r * 64 + ic) * 34 + x] = v;
    }
    __syncthreads();
    int lane = t & 63, ow = lane & 31, rr = lane >> 5;
    int oc0 = __builtin_amdgcn_readfirstlane((t >> 6) * 8);
    float acc[8];
    #pragma unroll
    for (int j = 0; j < 8; ++j) acc[j] = bias1[oc0 + j];
    for (int ic = 0; ic < 64; ++ic) {
      #pragma unroll
      for (int ky = 0; ky < 3; ++ky) {
        #pragma unroll
        for (int kx = 0; kx < 3; ++kx) {
          float iv = ins[((rr + ky) * 64 + ic) * 34 + ow + kx];
          const float* wr = wt1 + (ic * 9 + ky * 3 + kx) * 32 + oc0;
          #pragma unroll
          for (int j = 0; j < 8; ++j) acc[j] = fmaf(iv, wr[j], acc[j]);
        }
      }
    }
    if (ow < 30) {
      #pragma unroll
      for (int j = 0; j < 8; ++j) d1s[(rr * 32 + oc0 + j) * 32 + ow] = fmaxf(acc[j], 0.f);
    }
    __syncthreads();
    for (int e = t; e < 600; e += 256) {
      int r = e / 300, rem = e % 300, o = rem / 30, ow2 = rem % 30;
      float a2 = b2[o];
      #pragma unroll
      for (int ic = 0; ic < 32; ++ic) a2 += d1s[(r * 32 + ic) * 32 + ow2] * w2[ic * 10 + o];
      out_pred[(size_t)(b * 10 + o) * 900 + (oh0 + r) * 30 + ow2] = a2;
    }
  }
}

// ---- K cw: broadcast color_weights [B,900,900] (nontemporal) --------------
__global__ void k_cw(const unsigned char* __restrict__ stash, int sstride,
                     float* __restrict__ out2) {
  int blk = blockIdx.x;
  int b = blk / 60, rc = blk % 60;
  int t = threadIdx.x;
  const unsigned char* sl = stash + (size_t)b * sstride;
  const int* sidx = (const int*)sl;
  const float* scw = (const float*)(sl + 3640);
  __shared__ float lut[10][900];
  __shared__ unsigned char cols[900];
  __shared__ float cwb[100];
  for (int i = t; i < 900; i += 256) cols[i] = (unsigned char)sidx[i];
  for (int i = t; i < 100; i += 256) cwb[i] = scw[i];
  __syncthreads();
  for (int i = t; i < 9000; i += 256) {
    int cq = i / 900, p = i % 900;
    lut[cq][p] = cwb[cq * 10 + cols[p]];
  }
  __syncthreads();
  int base = rc * 15;
  for (int i = t; i < 15 * 225; i += 256) {
    int r = i / 225, ch = i % 225;
    int p = base + r;
    int cq = cols[p];
    f32x4 v = *(const f32x4*)&lut[cq][ch * 4];
    __builtin_nontemporal_store(v, (f32x4*)&out2[(size_t)b * 810000 + (size_t)p * 900 + ch * 4]);
  }
}

// ---- K map: one-hot mapped_output (reads own stash slice, overwrites it) --
__global__ void k_map(const unsigned char* __restrict__ stash, int sstride,
                      float* __restrict__ out4) {
  int b = blockIdx.x, t = threadIdx.x;
  const unsigned char* sl = stash + (size_t)b * sstride;
  const int* sidx = (const int*)sl;
  const int* sncol = (const int*)(sl + 3600);
  __shared__ unsigned char scol[900];
  __shared__ int sn[10];
  for (int i = t; i < 900; i += 256) scol[i] = (unsigned char)sidx[i];
  if (t < 10) sn[t] = sncol[t];
  __syncthreads();
  for (int i = t; i < 9000; i += 256) {
    int ch = i / 900, p = i % 900;
    out4[(size_t)b * 9000 + i] = (sn[scol[p]] == ch) ? 1.0f : 0.0f;
  }
}

extern "C" void kernel_launch(void* const* d_in, const int* in_sizes, int n_in,
                              void* d_out, int out_size, void* d_ws, size_t ws_size,
                              hipStream_t stream) {
  const float* input_grid = (const float*)d_in[0];
  const float* embed      = (const float*)d_in[1];
  const float* in_proj_w  = (const float*)d_in[2];
  const float* in_proj_b  = (const float*)d_in[3];
  const float* out_proj_w = (const float*)d_in[4];
  const float* out_proj_b = (const float*)d_in[5];
  const float* conv1_w    = (const float*)d_in[6];
  const float* conv1_b    = (const float*)d_in[7];
  const float* conv2_w    = (const float*)d_in[8];
  const float* conv2_b    = (const float*)d_in[9];
  const float* lin1_w     = (const float*)d_in[10];
  const float* lin1_b     = (const float*)d_in[11];
  const float* lin2_w     = (const float*)d_in[12];
  const float* lin2_b     = (const float*)d_in[13];
  const float* dec1_w     = (const float*)d_in[14];
  const float* dec1_b     = (const float*)d_in[15];
  const float* bn_g       = (const float*)d_in[16];
  const float* bn_b       = (const float*)d_in[17];
  const float* dec2_w     = (const float*)d_in[18];
  const float* dec2_b     = (const float*)d_in[19];

  float* out      = (float*)d_out;
  float* out_pred = out;                  // 576,000
  float* out_cmap = out + 576000;         // 6,400
  float* out_cw   = out + 582400;         // 51,840,000
  float* out_map  = out + 52422400;       // 576,000

  // Scratch in out_cw head (dead until k_cw, which runs after k_back, the
  // last scratch reader). Stash in out_map (overwritten only by k_map, last).
  float* scr = out_cw;
  float* comb  = scr;               // 3,686,400
  float* s1    = scr + 3686400;     // 1,843,200
  float* AT    = scr + 5529600;     // 40,960
  float* ve    = scr + 5570560;     // 640
  float* S     = scr + 5571200;     // 400
  float* wt2   = scr + 5571600;     // 18,432
  float* wt1   = scr + 5590032;     // 18,432
  float* bias1 = scr + 5608464;     // 32
  float* gfp   = scr + 5608496;     // 61,440
  int*   cnt   = (int*)(scr + 5669936);  // 640
  unsigned char* stash = (unsigned char*)out_map;  // 64 x 36000 B

  k_front<<<1170, 256, 0, stream>>>(input_grid, embed, in_proj_w, in_proj_b,
                                    conv1_w, conv1_b, conv2_w, dec1_w, dec1_b,
                                    bn_g, bn_b, ve, S, wt2, wt1, bias1, cnt,
                                    s1, stash, 36000);
  k_attn<<<B, 128, 0, stream>>>(S, ve, cnt, out_proj_w, out_proj_b, AT,
                                stash, 36000);
  k_c2<<<960, 256, 0, stream>>>(s1, wt2, conv2_b, AT, stash, 36000, comb, gfp);
  k_back<<<1024, 256, 0, stream>>>(comb, wt1, bias1, gfp, lin1_w, lin1_b,
                                   lin2_w, lin2_b, dec2_w, dec2_b,
                                   out_pred, out_cmap, stash, 36000);
  k_cw<<<B * 60, 256, 0, stream>>>(stash, 36000, out_cw);
  k_map<<<B, 256, 0, stream>>>(stash, 36000, out_map);
}

// Round 17
// 179.514 us; speedup vs baseline: 3.8190x; 1.1792x over previous
//
#include <hip/hip_runtime.h>
#include <cstddef>

#define B 64
#define NC 10
#define L 900

typedef float f32x4 __attribute__((ext_vector_type(4)));

// ---- scratch layout (float offsets) ----
#define SCR_COMB   0          // 3,686,400
#define SCR_S1     3686400    // 1,843,200
#define SCR_AT     5529600    // 40,960
#define SCR_VE     5570560    // 640
#define SCR_S      5571200    // 400
#define SCR_WT2    5571600    // 18,432
#define SCR_WT1    5590032    // 18,432
#define SCR_BIAS1  5608464    // 32
#define SCR_GFP    5608496    // 61,440
#define SCR_CNT    5669936    // 640 ints
#define SCR_FLOATS 5670576

// ---- K front: block-specialized independent setup work --------------------
// blocks 0: qkv/score tables | 1..145: wt2/wt1/bias1 | 146..209: per-image
// argmax+hist | 210..1169: conv1
__global__ __launch_bounds__(256) void k_front(
    const float* __restrict__ g, const float* __restrict__ embed,
    const float* __restrict__ ipw, const float* __restrict__ ipb,
    const float* __restrict__ cw1, const float* __restrict__ c1b,
    const float* __restrict__ cw2, const float* __restrict__ dw,
    const float* __restrict__ db, const float* __restrict__ bng,
    const float* __restrict__ bnb,
    float* __restrict__ scr, unsigned char* __restrict__ stash) {
  int bid = blockIdx.x, t = threadIdx.x;
  __shared__ float smem[4352];
  if (bid == 0) {
    float* emb = smem; float* q = smem + 640; float* k = smem + 1280;
    float* ve = scr + SCR_VE; float* S = scr + SCR_S;
    for (int i = t; i < 640; i += 256) emb[i] = embed[i];
    __syncthreads();
    for (int row = t; row < 192; row += 256) {
      int which = row >> 6, d = row & 63;
      for (int c = 0; c < 10; ++c) {
        float acc = ipb[row];
        for (int j = 0; j < 64; ++j) acc += emb[c * 64 + j] * ipw[row * 64 + j];
        if (which == 0) q[c * 64 + d] = acc;
        else if (which == 1) k[c * 64 + d] = acc;
        else ve[c * 64 + d] = acc;
      }
    }
    __syncthreads();
    for (int i = t; i < 400; i += 256) {
      int h = i / 100, r = i % 100, cq = r / 10, ck = r % 10;
      float acc = 0.f;
      for (int e = 0; e < 16; ++e)
        acc += q[cq * 64 + h * 16 + e] * k[ck * 64 + h * 16 + e];
      S[i] = acc * 0.25f;
    }
  } else if (bid <= 145) {
    int i = (bid - 1) * 256 + t;
    if (i < 18432) {
      int r = i / 64, oc = i % 64;
      scr[SCR_WT2 + r * 64 + oc] = cw2[oc * 288 + r];
    } else if (i < 36864) {
      int e = i - 18432, r = e / 32, oc = e % 32;
      int ic = r / 9, kk = r % 9, ky = kk / 3, kx = kk % 3;
      float s = bng[oc] / sqrtf(1.f + 1e-5f);
      scr[SCR_WT1 + r * 32 + oc] = dw[((ic * 32 + oc) * 3 + (2 - ky)) * 3 + (2 - kx)] * s;
    } else if (i < 36896) {
      int oc = i - 36864;
      float s = bng[oc] / sqrtf(1.f + 1e-5f);
      scr[SCR_BIAS1 + oc] = db[oc] * s + bnb[oc];
    }
  } else if (bid <= 209) {
    int b = bid - 146;
    int* hist = (int*)smem;
    int* cnt = (int*)(scr + SCR_CNT);
    if (t < 10) hist[t] = 0;
    __syncthreads();
    const float* gb = g + (size_t)b * NC * L;
    int* sidx = (int*)(stash + (size_t)b * 36000);
    for (int p = t; p < L; p += 256) {
      float best = gb[p]; int bi = 0;
      for (int c = 1; c < NC; ++c) {
        float v = gb[c * L + p];
        if (v > best) { best = v; bi = c; }
      }
      sidx[p] = bi;
      atomicAdd(&hist[bi], 1);
    }
    __syncthreads();
    if (t < 10) cnt[b * NC + t] = hist[t];
  } else {
    int blk = bid - 210, b = blk / 15, pr = blk % 15, oh0 = pr * 2;
    float* ins = smem;          // [4][10][34] = 1360
    float* ws = smem + 1360;    // 2880 raw conv1_w [oc][ic][3][3]
    float* s1 = scr + SCR_S1;
    for (int i = t; i < 2880; i += 256) ws[i] = cw1[i];
    for (int e = t; e < 1360; e += 256) {
      int r = e / 340, rem = e % 340, ic = rem / 34, x = rem % 34;
      int y = oh0 + r - 1, gx = x - 1;
      float v = 0.f;
      if (y >= 0 && y < 30 && gx >= 0 && gx < 30)
        v = g[(size_t)(b * 10 + ic) * 900 + y * 30 + gx];
      ins[(r * 10 + ic) * 34 + x] = v;
    }
    __syncthreads();
    int lane = t & 63, ow = lane & 31, rr = lane >> 5;
    int oc0 = __builtin_amdgcn_readfirstlane((t >> 6) * 8);
    float acc[8];
    #pragma unroll
    for (int j = 0; j < 8; ++j) acc[j] = c1b[oc0 + j];
    for (int ic = 0; ic < 10; ++ic) {
      #pragma unroll
      for (int ky = 0; ky < 3; ++ky) {
        #pragma unroll
        for (int kx = 0; kx < 3; ++kx) {
          float iv = ins[((rr + ky) * 10 + ic) * 34 + ow + kx];
          #pragma unroll
          for (int j = 0; j < 8; ++j)
            acc[j] = fmaf(iv, ws[((oc0 + j) * 10 + ic) * 9 + ky * 3 + kx], acc[j]);
        }
      }
    }
    if (ow < 30) {
      #pragma unroll
      for (int j = 0; j < 8; ++j)
        s1[(size_t)(b * 32 + oc0 + j) * 900 + (oh0 + rr) * 30 + ow] = fmaxf(acc[j], 0.f);
    }
  }
}

// ---- K attn: per-image A, CW->stash, ctx, AT ------------------------------
__global__ void k_attn(const float* __restrict__ S, const float* __restrict__ ve,
                       const int* __restrict__ cnt,
                       const float* __restrict__ opw, const float* __restrict__ opb,
                       float* __restrict__ AT, unsigned char* __restrict__ stash) {
  int b = blockIdx.x, t = threadIdx.x;  // 128 threads
  float* scw = (float*)(stash + (size_t)b * 36000 + 3640);
  __shared__ float A[4][10][10];
  __shared__ float cf[10];
  __shared__ float ctx[10][64];
  if (t < 10) cf[t] = (float)cnt[b * 10 + t];
  __syncthreads();
  if (t < 40) {
    int h = t / 10, cq = t % 10;
    const float* Sr = S + (h * 10 + cq) * 10;
    float m = -1e30f;
    for (int c = 0; c < 10; ++c) if (cf[c] > 0.f) m = fmaxf(m, Sr[c]);
    float e[10]; float Z = 0.f;
    for (int c = 0; c < 10; ++c) { e[c] = expf(Sr[c] - m); Z += cf[c] * e[c]; }
    float inv = 1.f / Z;
    for (int c = 0; c < 10; ++c) A[h][cq][c] = e[c] * inv;
  }
  __syncthreads();
  if (t < 100) {
    int cq = t / 10, ck = t % 10;
    scw[t] = 0.25f * (A[0][cq][ck] + A[1][cq][ck] + A[2][cq][ck] + A[3][cq][ck]);
  }
  for (int i = t; i < 640; i += 128) {
    int cq = i >> 6, dd = i & 63, h = dd >> 4;
    float acc = 0.f;
    for (int ck = 0; ck < 10; ++ck) acc += A[h][cq][ck] * cf[ck] * ve[ck * 64 + dd];
    ctx[cq][dd] = acc;
  }
  __syncthreads();
  for (int i = t; i < 640; i += 128) {
    int cq = i >> 6, dd = i & 63;
    float acc = opb[dd];
    for (int e = 0; e < 64; ++e) acc += ctx[cq][e] * opw[dd * 64 + e];
    AT[(b * 10 + cq) * 64 + dd] = acc;
  }
}

// ---- K c2: conv2 32->64 + relu + AT add + gf partial reduce ---------------
__global__ __launch_bounds__(256) void k_c2(const float* __restrict__ scr_s1,
                                            const float* __restrict__ wt2,
                                            const float* __restrict__ cb,
                                            const float* __restrict__ AT,
                                            const unsigned char* __restrict__ stash,
                                            float* __restrict__ comb,
                                            float* __restrict__ gfp) {
  int blk = blockIdx.x, b = blk / 15, pr = blk % 15, oh0 = pr * 2;
  int t = threadIdx.x;
  __shared__ float ins[4][32][34];
  for (int e = t; e < 4352; e += 256) {
    int r = e / 1088, rem = e % 1088, ic = rem / 34, x = rem % 34;
    int y = oh0 + r - 1, gx = x - 1;
    float v = 0.f;
    if (y >= 0 && y < 30 && gx >= 0 && gx < 30)
      v = scr_s1[(size_t)(b * 32 + ic) * 900 + y * 30 + gx];
    ins[r][ic][x] = v;
  }
  __syncthreads();
  int lane = t & 63, ow = lane & 31, rr = lane >> 5;
  int oc0 = __builtin_amdgcn_readfirstlane((t >> 6) * 16);
  float acc[16];
  #pragma unroll
  for (int j = 0; j < 16; ++j) acc[j] = cb[oc0 + j];
  for (int ic = 0; ic < 32; ++ic) {
    #pragma unroll
    for (int ky = 0; ky < 3; ++ky) {
      #pragma unroll
      for (int kx = 0; kx < 3; ++kx) {
        float iv = ins[rr + ky][ic][ow + kx];
        const float* wr = wt2 + (ic * 9 + ky * 3 + kx) * 64 + oc0;
        #pragma unroll
        for (int j = 0; j < 16; ++j) acc[j] = fmaf(iv, wr[j], acc[j]);
      }
    }
  }
  float outv[16];
  if (ow < 30) {
    const int* sidx = (const int*)(stash + (size_t)b * 36000);
    int c = sidx[(oh0 + rr) * 30 + ow];
    const float* at = AT + ((size_t)b * 10 + c) * 64 + oc0;
    #pragma unroll
    for (int j = 0; j < 16; ++j) {
      outv[j] = fmaxf(acc[j], 0.f) + at[j];
      comb[(size_t)(b * 64 + oc0 + j) * 900 + (oh0 + rr) * 30 + ow] = outv[j];
    }
  } else {
    #pragma unroll
    for (int j = 0; j < 16; ++j) outv[j] = 0.f;
  }
  #pragma unroll
  for (int j = 0; j < 16; ++j) {
    float v = outv[j];
    for (int o = 32; o; o >>= 1) v += __shfl_down(v, o, 64);
    if (lane == 0) gfp[(b * 15 + pr) * 64 + oc0 + j] = v;
  }
}

// ---- K back: block-specialized mlp | dec1+pred | cw -----------------------
// blocks 0..63: mlp | 64..1023: d1 | 1024..4863: cw (contiguous segments)
__global__ __launch_bounds__(256) void k_back(
    const float* __restrict__ scr,
    const float* __restrict__ l1w, const float* __restrict__ l1b,
    const float* __restrict__ l2w, const float* __restrict__ l2b,
    const float* __restrict__ w2, const float* __restrict__ b2,
    float* __restrict__ out_pred, float* __restrict__ out_cm,
    float* __restrict__ out_cw2, unsigned char* __restrict__ stash) {
  int bid = blockIdx.x, t = threadIdx.x;
  __shared__ float smem[10880];
  if (bid < 64) {
    int b = bid;
    float* gfl = smem; float* hmid = smem + 64; float* lg = smem + 192;
    const float* gfp = scr + SCR_GFP;
    if (t < 64) {
      float a = 0.f;
      for (int pr = 0; pr < 15; ++pr) a += gfp[(b * 15 + pr) * 64 + t];
      gfl[t] = a * (1.f / 900.f);
    }
    __syncthreads();
    if (t < 128) {
      float acc = l1b[t];
      for (int j = 0; j < 64; ++j) acc += gfl[j] * l1w[t * 64 + j];
      hmid[t] = fmaxf(acc, 0.f);
    }
    __syncthreads();
    if (t < 100) {
      float acc = l2b[t];
      for (int j = 0; j < 128; ++j) acc += hmid[j] * l2w[t * 128 + j];
      lg[t] = acc;
    }
    __syncthreads();
    if (t < 10) {
      float m = lg[t * 10]; int am = 0;
      for (int j = 1; j < 10; ++j) {
        float v = lg[t * 10 + j];
        if (v > m) { m = v; am = j; }
      }
      float e[10]; float Z = 0.f;
      for (int j = 0; j < 10; ++j) { e[j] = expf(lg[t * 10 + j] - m); Z += e[j]; }
      float inv = 1.f / Z;
      for (int j = 0; j < 10; ++j) out_cm[(b * 10 + t) * 10 + j] = e[j] * inv;
      ((int*)(stash + (size_t)b * 36000 + 3600))[t] = am;
    }
  } else if (bid < 1024) {
    int blk = bid - 64, b = blk / 15, pr = blk % 15, oh0 = pr * 2;
    float* ins = smem;            // [4][64][34] = 8704
    float* d1s = smem + 8704;     // [2][32][32] = 2048
    const float* comb = scr + SCR_COMB;
    const float* wt1 = scr + SCR_WT1;
    const float* bias1 = scr + SCR_BIAS1;
    for (int e = t; e < 8704; e += 256) {
      int r = e / 2176, rem = e % 2176, ic = rem / 34, x = rem % 34;
      int y = oh0 + r - 1, gx = x - 1;
      float v = 0.f;
      if (y >= 0 && y < 30 && gx >= 0 && gx < 30)
        v = comb[(size_t)(b * 64 + ic) * 900 + y * 30 + gx];
      ins[(r * 64 + ic) * 34 + x] = v;
    }
    __syncthreads();
    int lane = t & 63, ow = lane & 31, rr = lane >> 5;
    int oc0 = __builtin_amdgcn_readfirstlane((t >> 6) * 8);
    float acc[8];
    #pragma unroll
    for (int j = 0; j < 8; ++j) acc[j] = bias1[oc0 + j];
    for (int ic = 0; ic < 64; ++ic) {
      #pragma unroll
      for (int ky = 0; ky < 3; ++ky) {
        #pragma unroll
        for (int kx = 0; kx < 3; ++kx) {
          float iv = ins[((rr + ky) * 64 + ic) * 34 + ow + kx];
          const float* wr = wt1 + (ic * 9 + ky * 3 + kx) * 32 + oc0;
          #pragma unroll
          for (int j = 0; j < 8; ++j) acc[j] = fmaf(iv, wr[j], acc[j]);
        }
      }
    }
    if (ow < 30) {
      #pragma unroll
      for (int j = 0; j < 8; ++j) d1s[(rr * 32 + oc0 + j) * 32 + ow] = fmaxf(acc[j], 0.f);
    }
    __syncthreads();
    for (int e = t; e < 600; e += 256) {
      int r = e / 300, rem = e % 300, o = rem / 30, ow2 = rem % 30;
      float a2 = b2[o];
      #pragma unroll
      for (int ic = 0; ic < 32; ++ic) a2 += d1s[(r * 32 + ic) * 32 + ow2] * w2[ic * 10 + o];
      out_pred[(size_t)(b * 10 + o) * 900 + (oh0 + r) * 30 + ow2] = a2;
    }
  } else {
    int blk = bid - 1024, b = blk / 60, rc = blk % 60;
    float* lut = smem;                                   // [10][900]
    float* cwb = smem + 9000;                            // 100
    unsigned char* cols = (unsigned char*)(smem + 9100); // 900 B
    const unsigned char* sl = stash + (size_t)b * 36000;
    const int* sidx = (const int*)sl;
    const float* scw = (const float*)(sl + 3640);
    for (int i = t; i < 900; i += 256) cols[i] = (unsigned char)sidx[i];
    for (int i = t; i < 100; i += 256) cwb[i] = scw[i];
    __syncthreads();
    for (int i = t; i < 9000; i += 256) {
      int cq = i / 900, p = i % 900;
      lut[cq * 900 + p] = cwb[cq * 10 + cols[p]];
    }
    __syncthreads();
    int base = rc * 15;
    for (int i = t; i < 15 * 225; i += 256) {
      int r = i / 225, ch = i % 225;
      int p = base + r;
      int cq = cols[p];
      f32x4 v = *(const f32x4*)&lut[cq * 900 + ch * 4];
      __builtin_nontemporal_store(v, (f32x4*)&out_cw2[(size_t)b * 810000 + (size_t)p * 900 + ch * 4]);
    }
  }
}

// ---- K cw (fallback only): broadcast color_weights ------------------------
__global__ void k_cw(const unsigned char* __restrict__ stash,
                     float* __restrict__ out2) {
  int blk = blockIdx.x;
  int b = blk / 60, rc = blk % 60;
  int t = threadIdx.x;
  const unsigned char* sl = stash + (size_t)b * 36000;
  const int* sidx = (const int*)sl;
  const float* scw = (const float*)(sl + 3640);
  __shared__ float lut[10][900];
  __shared__ unsigned char cols[900];
  __shared__ float cwb[100];
  for (int i = t; i < 900; i += 256) cols[i] = (unsigned char)sidx[i];
  for (int i = t; i < 100; i += 256) cwb[i] = scw[i];
  __syncthreads();
  for (int i = t; i < 9000; i += 256) {
    int cq = i / 900, p = i % 900;
    lut[cq][p] = cwb[cq * 10 + cols[p]];
  }
  __syncthreads();
  int base = rc * 15;
  for (int i = t; i < 15 * 225; i += 256) {
    int r = i / 225, ch = i % 225;
    int p = base + r;
    int cq = cols[p];
    f32x4 v = *(const f32x4*)&lut[cq][ch * 4];
    __builtin_nontemporal_store(v, (f32x4*)&out2[(size_t)b * 810000 + (size_t)p * 900 + ch * 4]);
  }
}

// ---- K map: one-hot mapped_output f32 -------------------------------------
__global__ void k_map(const unsigned char* __restrict__ stash,
                      float* __restrict__ out4) {
  int b = blockIdx.x, t = threadIdx.x;
  const unsigned char* sl = stash + (size_t)b * 36000;
  const int* sidx = (const int*)sl;
  const int* sncol = (const int*)(sl + 3600);
  __shared__ unsigned char scol[900];
  __shared__ int sn[10];
  for (int i = t; i < 900; i += 256) scol[i] = (unsigned char)sidx[i];
  if (t < 10) sn[t] = sncol[t];
  __syncthreads();
  for (int i = t; i < 9000; i += 256) {
    int ch = i / 900, p = i % 900;
    out4[(size_t)b * 9000 + i] = (sn[scol[p]] == ch) ? 1.0f : 0.0f;
  }
}

extern "C" void kernel_launch(void* const* d_in, const int* in_sizes, int n_in,
                              void* d_out, int out_size, void* d_ws, size_t ws_size,
                              hipStream_t stream) {
  const float* input_grid = (const float*)d_in[0];
  const float* embed      = (const float*)d_in[1];
  const float* in_proj_w  = (const float*)d_in[2];
  const float* in_proj_b  = (const float*)d_in[3];
  const float* out_proj_w = (const float*)d_in[4];
  const float* out_proj_b = (const float*)d_in[5];
  const float* conv1_w    = (const float*)d_in[6];
  const float* conv1_b    = (const float*)d_in[7];
  const float* conv2_w    = (const float*)d_in[8];
  const float* conv2_b    = (const float*)d_in[9];
  const float* lin1_w     = (const float*)d_in[10];
  const float* lin1_b     = (const float*)d_in[11];
  const float* lin2_w     = (const float*)d_in[12];
  const float* lin2_b     = (const float*)d_in[13];
  const float* dec1_w     = (const float*)d_in[14];
  const float* dec1_b     = (const float*)d_in[15];
  const float* bn_g       = (const float*)d_in[16];
  const float* bn_b       = (const float*)d_in[17];
  const float* dec2_w     = (const float*)d_in[18];
  const float* dec2_b     = (const float*)d_in[19];

  float* out      = (float*)d_out;
  float* out_pred = out;                  // 576,000
  float* out_cmap = out + 576000;         // 6,400
  float* out_cw   = out + 582400;         // 51,840,000
  float* out_map  = out + 52422400;       // 576,000

  // Preferred (measured 179.3 µs): all scratch in d_ws (ws_size >= 22.7 MB
  // confirmed by R11 vs R16 timing); cw runs inside k_back overlapped with d1.
  // Fallback (measured ~212 µs): all scratch in dead out_cw region.
  bool ws_ok = ws_size >= (size_t)SCR_FLOATS * 4;
  float* scr = ws_ok ? (float*)d_ws : out_cw;
  unsigned char* stash = (unsigned char*)out_map;  // 64 slices x 36000 B

  k_front<<<1170, 256, 0, stream>>>(input_grid, embed, in_proj_w, in_proj_b,
                                    conv1_w, conv1_b, conv2_w, dec1_w, dec1_b,
                                    bn_g, bn_b, scr, stash);
  k_attn<<<B, 128, 0, stream>>>(scr + SCR_S, scr + SCR_VE, (int*)(scr + SCR_CNT),
                                out_proj_w, out_proj_b, scr + SCR_AT, stash);
  k_c2<<<960, 256, 0, stream>>>(scr + SCR_S1, scr + SCR_WT2, conv2_b,
                                scr + SCR_AT, stash, scr + SCR_COMB, scr + SCR_GFP);
  k_back<<<ws_ok ? 4864 : 1024, 256, 0, stream>>>(scr, lin1_w, lin1_b, lin2_w, lin2_b,
                                                  dec2_w, dec2_b, out_pred, out_cmap,
                                                  out_cw, stash);
  if (!ws_ok) k_cw<<<B * 60, 256, 0, stream>>>(stash, out_cw);
  k_map<<<B, 256, 0, stream>>>(stash, out_map);
}